// Round 4
// baseline (830.296 us; speedup 1.0000x reference)
//
#include <hip/hip_runtime.h>
#include <hip/hip_bf16.h>

// Sizes (fixed by the reference)
//  V=32000, T=48, E=128, HID=256, H=128, B=256, L=512, 4H=512
typedef unsigned short ushort_t;
typedef unsigned int uint_t;
typedef __bf16 bf16x8 __attribute__((ext_vector_type(8)));
typedef float f32x4 __attribute__((ext_vector_type(4)));
typedef float f32x16 __attribute__((ext_vector_type(16)));

#define L2E 1.44269504088896340736f
#define LN2 0.69314718055994530942f

// LDS-only barrier: does NOT drain vmcnt -> global loads/stores stay in flight.
#define WGBAR() __asm__ volatile("s_waitcnt lgkmcnt(0)\n\ts_barrier" ::: "memory")

static __device__ __forceinline__ float fexp2(float x) { return __builtin_amdgcn_exp2f(x); }
static __device__ __forceinline__ float flog2(float x) { return __builtin_amdgcn_logf(x); }
static __device__ __forceinline__ float frcp (float x) { return __builtin_amdgcn_rcpf(x); }

static __device__ __forceinline__ float sigm(float x) {
  return frcp(1.0f + fexp2(-L2E * x));
}
static __device__ __forceinline__ float tanha(float x) {
  return 1.0f - 2.0f * frcp(1.0f + fexp2(2.0f * L2E * x));
}

static __device__ __forceinline__ ushort_t f2bf(float f) {
  union { float f; uint_t u; } v; v.f = f;
  uint_t u = v.u;
  uint_t r = (u + 0x7fffu + ((u >> 16) & 1u)) >> 16;  // RNE
  return (ushort_t)r;
}
static __device__ __forceinline__ bf16x8 pack8(float4 a, float4 b) {
  uint4 u = make_uint4(
      (uint_t)f2bf(a.x) | ((uint_t)f2bf(a.y) << 16),
      (uint_t)f2bf(a.z) | ((uint_t)f2bf(a.w) << 16),
      (uint_t)f2bf(b.x) | ((uint_t)f2bf(b.y) << 16),
      (uint_t)f2bf(b.z) | ((uint_t)f2bf(b.w) << 16));
  return __builtin_bit_cast(bf16x8, u);
}
static __device__ __forceinline__ bf16x8 zero8() {
  uint4 z = make_uint4(0u, 0u, 0u, 0u);
  return __builtin_bit_cast(bf16x8, z);
}
static __device__ __forceinline__ uint2 pack4(float4 a) {
  return make_uint2((uint_t)f2bf(a.x) | ((uint_t)f2bf(a.y) << 16),
                    (uint_t)f2bf(a.z) | ((uint_t)f2bf(a.w) << 16));
}

// DPP row-rotate-right by K within 16-lane rows (K=0 -> identity).
template <int K>
static __device__ __forceinline__ float rotk(float x) {
  if constexpr (K == 0) {
    return x;
  } else {
    return __builtin_bit_cast(float, __builtin_amdgcn_update_dpp(
        0, __builtin_bit_cast(int, x), 0x120 + K, 0xf, 0xf, true));
  }
}

// ---------------------------------------------------------------------------
// K2 v8: fully-fused BiLSTM. grid = 256 WGs x 512 thr; wg>>7 = dir,
// (wg&127)*2 = 2 batch rows. v8 = v7 + production-A hoist:
//  - xs[pcon] is stable for the whole 8-step block (written at s6 of block
//    i-1, next overwritten at s6 of block i+1), so the production A-fragment
//    (4x ds_read_b128) is loaded ONCE per block into afp[4] instead of
//    2 reads per step (saves 12 DS ops/block/wave = ~12 ops/CU/step).
// Raw lgkm-only barriers keep global loads/stores in flight across steps.
// ---------------------------------------------------------------------------
__global__ __launch_bounds__(512, 2) void k2_lstm(
    const int* __restrict__ words, const float* __restrict__ emb,
    const float* __restrict__ Wih_f, const float* __restrict__ Whh_f,
    const float* __restrict__ bih_f, const float* __restrict__ bhh_f,
    const float* __restrict__ Wih_b, const float* __restrict__ Whh_b,
    const float* __restrict__ bih_b, const float* __restrict__ bhh_b,
    ushort_t* __restrict__ h_f, ushort_t* __restrict__ h_b) {
  const int wg = blockIdx.x;
  const int dir = wg >> 7;
  const int r0 = (wg & 127) << 1;
  const float* Whh = dir ? Whh_b : Whh_f;
  const float* Wih = dir ? Wih_b : Wih_f;
  const float* bih = dir ? bih_b : bih_f;
  const float* bhh = dir ? bhh_b : bhh_f;
  ushort_t* hout = dir ? h_b : h_f;

  const int tid = threadIdx.x;
  const int w = tid >> 6;        // wave 0..7
  const int lane = tid & 63;
  const int l15 = lane & 15;
  const int kq = lane >> 4;      // 0..3

  __shared__ __align__(16) ushort_t hx[2][2][136];      //  1,088 B
  __shared__ __align__(16) ushort_t xp[2][16][128][4];  // 32,768 B
  __shared__ __align__(16) ushort_t xs[2][16][136];     //  8,704 B

  // ---- register-resident weight fragments (bf16), [quadrant][K-chunk] ----
  // B layout (16x16x32): col n = lane&15, k = (lane>>4)*8 + j
  bf16x8 wfh[4][4], wfx[4][4];
  float biasP[4];   // production bias for col w*16+l15, quadrant Q
#pragma unroll
  for (int Q = 0; Q < 4; ++Q) {
    const int n = Q * 128 + w * 16 + l15;
    biasP[Q] = bih[n] + bhh[n];
#pragma unroll
    for (int c = 0; c < 4; ++c) {
      const int k0 = c * 32 + kq * 8;
      const float* sh = Whh + n * 128 + k0;
      const float* sx = Wih + n * 128 + k0;
      wfh[Q][c] = pack8(*(const float4*)sh, *(const float4*)(sh + 4));
      wfx[Q][c] = pack8(*(const float4*)sx, *(const float4*)(sx + 4));
    }
  }

  const int ur = (lane >> 4) & 1;
  const int uj = w * 16 + l15;
  float cst = 0.f;

  // staging thread mapping: 512 thr cover 16 rows x 128 cols (4 floats each)
  const int sm = tid >> 5;          // xs row 0..15  (tl = sm>>1, r = sm&1)
  const int sc = (tid & 31) * 4;    // col 0..124
  const int str = r0 + (sm & 1);
  const int stl = sm >> 1;

  // production pack registers (live across the 4 Q sub-phases of a block)
  uint_t pd0[4], pd1[4];
  f32x4 pc = {0.f, 0.f, 0.f, 0.f};

  // ---- prologue ----
  if (tid < 256) hx[0][tid >> 7][tid & 127] = 0;   // h(-1) = 0
  {  // stage xs[1] = x(block 0)
    const int tg = stl;
    const int tf = dir ? (511 - tg) : tg;
    const int word = words[str * 512 + tf];
    float4 av = *(const float4*)(emb + (size_t)word * 128 + sc);
    *(uint2*)&xs[1][sm][sc] = pack4(av);
  }
  WGBAR();
  // produce xp[0] from xs[1] (16 dense MFMAs/wave), bias in C-init
#pragma unroll
  for (int Q = 0; Q < 4; ++Q) {
    f32x4 pc0 = {biasP[Q], biasP[Q], biasP[Q], biasP[Q]};
#pragma unroll
    for (int c = 0; c < 4; ++c) {
      bf16x8 af = __builtin_bit_cast(bf16x8, *(const uint4*)&xs[1][l15][kq * 8 + c * 32]);
      pc0 = __builtin_amdgcn_mfma_f32_16x16x32_bf16(af, wfx[Q][c], pc0, 0, 0, 0);
    }
#pragma unroll
    for (int rr = 0; rr < 4; ++rr) {
      const uint_t bb = (uint_t)f2bf(pc0[rr]);
      if (Q == 0) pd0[rr] = bb;
      else if (Q == 1) pd0[rr] |= bb << 16;
      else if (Q == 2) pd1[rr] = bb;
      else pd1[rr] |= bb << 16;
    }
  }
#pragma unroll
  for (int rr = 0; rr < 4; ++rr)
    *(uint2*)&xp[0][kq * 4 + rr][uj][0] = make_uint2(pd0[rr], pd1[rr]);
  {  // stage xs[0] = x(block 1)
    const int tg = 8 + stl;
    const int tf = dir ? (511 - tg) : tg;
    const int word = words[str * 512 + tf];
    float4 av = *(const float4*)(emb + (size_t)word * 128 + sc);
    *(uint2*)&xs[0][sm][sc] = pack4(av);
  }
  WGBAR();

  int sword = 0;
  float4 se0 = make_float4(0.f, 0.f, 0.f, 0.f);

#pragma unroll 1
  for (int i = 0; i < 64; ++i) {   // 64 blocks of 8 steps
    const int pcon = i & 1;        // consume xp[pcon]; production reads xs[pcon]
    const int ppro = pcon ^ 1;     // produce xp[ppro]; staging writes xs[ppro]
    // ---- per-block hoist: production A-fragments (xs[pcon] stable all block)
    bf16x8 afp[4];
    if (i < 63) {
#pragma unroll
      for (int c = 0; c < 4; ++c)
        afp[c] = __builtin_bit_cast(bf16x8, *(const uint4*)&xs[pcon][l15][kq * 8 + c * 32]);
    }
#pragma unroll
    for (int s = 0; s < 8; ++s) {
      const int t = i * 8 + s;
      const int p = t & 1;
      // xp consumption: one b64 read (Q0..Q3 packed for this lane's (ur,uj))
      const uint2 xq = *(const uint2*)&xp[pcon][2 * s + ur][uj][0];
      // staging pipeline for x(block i+2): word @s0, emb @s2, LDS write @s6
      if (i < 62) {
        if (s == 0) {
          const int tg = (i + 2) * 8 + stl;
          const int tf = dir ? (511 - tg) : tg;
          sword = words[str * 512 + tf];
        }
        if (s == 2) se0 = *(const float4*)(emb + (size_t)sword * 128 + sc);
        if (s == 6) *(uint2*)&xs[ppro][sm][sc] = pack4(se0);
      }
      // ---- recurrence MFMAs: gates_h = h @ Whh^T (K=128) ----
      f32x4 a0 = {0.f, 0.f, 0.f, 0.f}, a1 = a0, a2 = a0, a3 = a0;
      const ushort_t* abase = &hx[p][l15 & 1][kq * 8];
#pragma unroll
      for (int c = 0; c < 4; ++c) {
        bf16x8 af = __builtin_bit_cast(bf16x8, *(const uint4*)(abase + c * 32));
        a0 = __builtin_amdgcn_mfma_f32_16x16x32_bf16(af, wfh[0][c], a0, 0, 0, 0);
        a1 = __builtin_amdgcn_mfma_f32_16x16x32_bf16(af, wfh[1][c], a1, 0, 0, 0);
        a2 = __builtin_amdgcn_mfma_f32_16x16x32_bf16(af, wfh[2][c], a2, 0, 0, 0);
        a3 = __builtin_amdgcn_mfma_f32_16x16x32_bf16(af, wfh[3][c], a3, 0, 0, 0);
      }
      // ---- production MFMAs for block i+1 (independent; fills bubbles).
      //      A-fragments from afp regs; results buffered in pd0/pd1;
      //      single 4x b64 LDS write at s==7.
      if (i < 63) {
        const int Q = s >> 1;
        if ((s & 1) == 0) {
          pc = f32x4{biasP[Q], biasP[Q], biasP[Q], biasP[Q]};
          pc = __builtin_amdgcn_mfma_f32_16x16x32_bf16(afp[0], wfx[Q][0], pc, 0, 0, 0);
          pc = __builtin_amdgcn_mfma_f32_16x16x32_bf16(afp[1], wfx[Q][1], pc, 0, 0, 0);
        } else {
          pc = __builtin_amdgcn_mfma_f32_16x16x32_bf16(afp[2], wfx[Q][2], pc, 0, 0, 0);
          pc = __builtin_amdgcn_mfma_f32_16x16x32_bf16(afp[3], wfx[Q][3], pc, 0, 0, 0);
#pragma unroll
          for (int rr = 0; rr < 4; ++rr) {
            const uint_t bb = (uint_t)f2bf(pc[rr]);
            if (Q == 0) pd0[rr] = bb;
            else if (Q == 1) pd0[rr] |= bb << 16;
            else if (Q == 2) pd1[rr] = bb;
            else pd1[rr] |= bb << 16;
          }
          if (s == 7) {
#pragma unroll
            for (int rr = 0; rr < 4; ++rr)
              *(uint2*)&xp[ppro][kq * 4 + rr][uj][0] = make_uint2(pd0[rr], pd1[rr]);
          }
        }
      }
      // ---- gates: lane's own (ur,uj) pair -- reg[0]=batch0, reg[1]=batch1
      const float g0 = (ur ? a0[1] : a0[0]) + __builtin_bit_cast(float, xq.x << 16);
      const float g1 = (ur ? a1[1] : a1[0]) + __builtin_bit_cast(float, xq.x & 0xffff0000u);
      const float g2 = (ur ? a2[1] : a2[0]) + __builtin_bit_cast(float, xq.y << 16);
      const float g3 = (ur ? a3[1] : a3[0]) + __builtin_bit_cast(float, xq.y & 0xffff0000u);
      // activations (one chain per lane; lanes>=32 duplicate, stores guarded)
      const float si = sigm(g0), sf = sigm(g1), so = sigm(g3);
      const float tg = tanha(g2);
      cst = sf * cst + si * tg;
      const float h = so * tanha(cst);
      const ushort_t hb = f2bf(h);
      if (lane < 32) {
        hx[p ^ 1][ur][uj] = hb;
        const int tf = dir ? (511 - t) : t;
        hout[(tf * 256 + r0 + ur) * 128 + uj] = hb;  // stays in flight
      }
      WGBAR();
    }
  }
}

// ---------------------------------------------------------------------------
// K3: emis[t*256+b][48] = [h_f|h_b] @ Wout^T + bout  (fp32 out)
// Also zeroes the loss accumulator (block 0, thread 0) so K4 can atomicAdd.
// ---------------------------------------------------------------------------
__global__ __launch_bounds__(256, 2) void k3_emis(
    const ushort_t* __restrict__ h_f, const ushort_t* __restrict__ h_b,
    const float* __restrict__ Wout, const float* __restrict__ bout,
    float* __restrict__ emis, float* __restrict__ loss_out) {
  if (blockIdx.x == 0 && threadIdx.x == 0) loss_out[0] = 0.f;
  const int w = threadIdx.x >> 6;
  const int lane = threadIdx.x & 63;
  const int m31 = lane & 31;
  const int q = lane >> 5;
  const int Mbase = blockIdx.x * 128 + w * 32;

  bf16x8 bfr[2][16];
  float bo[2];
#pragma unroll
  for (int T = 0; T < 2; ++T) {
    const int n = T * 32 + m31;
    if (n < 48) {
      bo[T] = bout[n];
#pragma unroll
      for (int c = 0; c < 16; ++c) {
        const float* src = Wout + n * 256 + c * 16 + q * 8;
        bfr[T][c] = pack8(*(const float4*)src, *(const float4*)(src + 4));
      }
    } else {
      bo[T] = 0.f;
#pragma unroll
      for (int c = 0; c < 16; ++c) bfr[T][c] = zero8();
    }
  }
  f32x16 acc0{}, acc1{};
  const ushort_t* hrf = h_f + (long)(Mbase + m31) * 128;
  const ushort_t* hrb = h_b + (long)(Mbase + m31) * 128;
#pragma unroll
  for (int c = 0; c < 16; ++c) {
    const ushort_t* src = (c < 8) ? (hrf + c * 16 + q * 8) : (hrb + (c - 8) * 16 + q * 8);
    bf16x8 af = __builtin_bit_cast(bf16x8, *(const uint4*)src);
    acc0 = __builtin_amdgcn_mfma_f32_32x32x16_bf16(af, bfr[0][c], acc0, 0, 0, 0);
    acc1 = __builtin_amdgcn_mfma_f32_32x32x16_bf16(af, bfr[1][c], acc1, 0, 0, 0);
  }
#pragma unroll
  for (int T = 0; T < 2; ++T) {
    const int n = T * 32 + m31;
    if (n >= 48) continue;
    f32x16 A = T ? acc1 : acc0;
#pragma unroll
    for (int r = 0; r < 16; ++r) {
      const int row = (r & 3) + ((r >> 2) << 3) + (q << 2);
      emis[(long)(Mbase + row) * 48 + n] = A[r] + bo[T];
    }
  }
}

// ---------------------------------------------------------------------------
// K4 v7: fused CRF. wave 0 = forward algorithm (denominator), wave 1 = gold
// path score (numerator); per-block loss contribution atomicAdd'ed into out.
// Denominator matvec now uses a REGISTER all-gather instead of the LDS
// round-trip: dm[m] = shfl_xor(d, m*16) covers all 4 rows of 16 lanes;
// 15 DPP row_ror rotations per source expose all 64 lane values; per-lane
// coefficients pcr[m][k] are SELF-CALIBRATED in the prologue by running the
// identical gather on probe=laneid and reading back which source index lands
// in each (m,k) slot (semantics-proof), with pcr=0 for idx>=48 (junk lanes).
// Replaces {ds_write + 12 ds_read_b128 + lgkm-wait} (~270cy) with
// {4 shfl + 60 DPP} on the 512-step serial chain. 256 WGs x 128 thr.
// ---------------------------------------------------------------------------
#define K4_ROW(OP, m) \
  OP(m, 0) OP(m, 1) OP(m, 2) OP(m, 3) OP(m, 4) OP(m, 5) OP(m, 6) OP(m, 7) \
  OP(m, 8) OP(m, 9) OP(m, 10) OP(m, 11) OP(m, 12) OP(m, 13) OP(m, 14) OP(m, 15)
#define K4_ALL(OP) K4_ROW(OP, 0) K4_ROW(OP, 1) K4_ROW(OP, 2) K4_ROW(OP, 3)

__global__ void k4_crf(const int* __restrict__ words, const int* __restrict__ tags,
                       const float* __restrict__ emis, const float* __restrict__ trans,
                       const float* __restrict__ st, const float* __restrict__ et,
                       float* __restrict__ out) {
  const int b = blockIdx.x;
  const int tid = threadIdx.x;
  const int j = tid & 63;
  __shared__ float res[2];

  if (tid >= 64) {
    // ---- wave 1: numerator (gold path score) ----
    float s = 0.f;
    int cnt = 0;
#pragma unroll 1
    for (int s8 = 0; s8 < 8; ++s8) {
      const int t = j + (s8 << 6);
      const int wv = words[b * 512 + t];
      const int tg = tags[b * 512 + t];
      const bool mt = (wv != 0);
      cnt += mt ? 1 : 0;
      if (t == 0) {
        s += st[tg] + emis[b * 48 + tg];
      } else if (mt) {
        const int tp = tags[b * 512 + t - 1];
        s += trans[tp * 48 + tg] + emis[(t * 256 + b) * 48 + tg];
      }
    }
#pragma unroll
    for (int d = 32; d; d >>= 1) {
      s += __shfl_xor(s, d, 64);
      cnt += __shfl_xor(cnt, d, 64);
    }
    if (j == 0) {
      const int lt = tags[b * 512 + cnt - 1];
      res[1] = s + et[lt];
    }
  } else {
    // ---- wave 0: denominator, forward algorithm in linear domain ----
    const bool v = j < 48;

    // self-calibration: discover source index of each (m,k) gather slot
    float pcr[64];
    {
      float pm[4];
      const float pj = (float)j;
      pm[0] = pj;
      pm[1] = __shfl_xor(pj, 16, 64);
      pm[2] = __shfl_xor(pj, 32, 64);
      pm[3] = __shfl_xor(pj, 48, 64);
#define K4_CAL(m, k) { const int idx_ = (int)rotk<k>(pm[m]); \
      pcr[(m) * 16 + (k)] = (v && idx_ < 48) ? fexp2(trans[idx_ * 48 + j] * L2E) : 0.f; }
      K4_ALL(K4_CAL)
#undef K4_CAL
    }

    // mask bits: mb[q] bit s = (words[b*512 + q*64 + s] != 0)
    unsigned long long mb[8];
#pragma unroll
    for (int q = 0; q < 8; ++q)
      mb[q] = __ballot(words[b * 512 + q * 64 + j] != 0);

    float d = v ? fexp2((st[j] + emis[b * 48 + j]) * L2E) : 0.f;
    int S = 0, e_pend = 0;

    float em0 = v ? emis[(1 * 256 + b) * 48 + j] : 0.f;
    float em1 = v ? emis[(2 * 256 + b) * 48 + j] : 0.f;
    float em2 = v ? emis[(3 * 256 + b) * 48 + j] : 0.f;
    float em3 = v ? emis[(4 * 256 + b) * 48 + j] : 0.f;
    float Ecur = fexp2(em0 * L2E);

#pragma unroll 1
    for (int q = 0; q < 8; ++q) {
      const unsigned long long m = mb[q];
      const int s0 = (q == 0) ? 1 : 0;
#pragma unroll 1
      for (int s = s0; s < 64; ++s) {
        const int t = q * 64 + s;
        float E = Ecur;
        int eApp = 0;
        if ((s & 7) == 2) {   // fold lagged renorm into E (uniform branch)
          const float sc = __builtin_bit_cast(float, (uint_t)(127 - e_pend) << 23);
          E *= sc;
          eApp = e_pend;
        }
        const int tn = min(511, t + 4);
        em0 = em1; em1 = em2; em2 = em3;
        em3 = v ? emis[(tn * 256 + b) * 48 + j] : 0.f;  // vmcnt path, depth-4
        const float En = fexp2(em0 * L2E);              // E for t+1, off-chain

        // register all-gather matvec: nxt_j = sum_i d_i * P[i][j]
        float dm[4];
        dm[0] = d;
        dm[1] = __shfl_xor(d, 16, 64);
        dm[2] = __shfl_xor(d, 32, 64);
        dm[3] = __shfl_xor(d, 48, 64);
        float acc[8] = {0.f, 0.f, 0.f, 0.f, 0.f, 0.f, 0.f, 0.f};
#define K4_FMA(m, k) acc[((m) * 16 + (k)) & 7] = \
        fmaf(rotk<k>(dm[m]), pcr[(m) * 16 + (k)], acc[((m) * 16 + (k)) & 7]);
        K4_ALL(K4_FMA)
#undef K4_FMA
        const float nxt = (((acc[0] + acc[1]) + (acc[2] + acc[3])) +
                           ((acc[4] + acc[5]) + (acc[6] + acc[7]))) * E;
        if ((m >> s) & 1ull) {   // wave-uniform scalar branch, no memory
          d = v ? nxt : 0.f;
          S += eApp;
        }
        if ((s & 7) == 0) {      // lagged exponent measurement (any lane works)
          const int db = __builtin_amdgcn_readfirstlane(__builtin_bit_cast(int, d));
          e_pend = ((db >> 23) & 0xff) - 127;
        }
        Ecur = En;
      }
    }
    float uf = v ? d * fexp2(et[j] * L2E) : 0.f;
#pragma unroll
    for (int dd = 32; dd; dd >>= 1) uf += __shfl_xor(uf, dd, 64);
    if (j == 0) res[0] = ((float)S + flog2(uf)) * LN2;
  }
  __syncthreads();
  // loss = -mean(num - denom)  ->  accumulate (denom - num)/256
  if (tid == 0) atomicAdd(out, (res[0] - res[1]) * (1.0f / 256.0f));
}

// ---------------------------------------------------------------------------
extern "C" void kernel_launch(void* const* d_in, const int* in_sizes, int n_in,
                              void* d_out, int out_size, void* d_ws, size_t ws_size,
                              hipStream_t stream) {
  (void)in_sizes; (void)n_in; (void)out_size; (void)ws_size;
  const int*   words = (const int*)d_in[0];
  const int*   tags  = (const int*)d_in[1];
  // d_in[2] = mask (bool) -- unused; reconstructed as words != 0
  const float* emb   = (const float*)d_in[3];
  const float* Wih_f = (const float*)d_in[4];
  const float* Whh_f = (const float*)d_in[5];
  const float* bih_f = (const float*)d_in[6];
  const float* bhh_f = (const float*)d_in[7];
  const float* Wih_b = (const float*)d_in[8];
  const float* Whh_b = (const float*)d_in[9];
  const float* bih_b = (const float*)d_in[10];
  const float* bhh_b = (const float*)d_in[11];
  const float* Wout  = (const float*)d_in[12];
  const float* bout  = (const float*)d_in[13];
  const float* trans = (const float*)d_in[14];
  const float* st    = (const float*)d_in[15];
  const float* et    = (const float*)d_in[16];

  char* ws = (char*)d_ws;
  ushort_t* h_f   = (ushort_t*)(ws);                    // 33,554,432 B
  ushort_t* h_b   = (ushort_t*)(ws + 33554432);         // 33,554,432 B
  float*    emis  = (float*)   (ws + 67108864);         // 25,165,824 B
  // total ws needed: ~92.3 MB (within the known-good 125.8 MB envelope)

  k2_lstm <<<256, 512, 0, stream>>>(words, emb,
                                    Wih_f, Whh_f, bih_f, bhh_f,
                                    Wih_b, Whh_b, bih_b, bhh_b,
                                    h_f, h_b);
  k3_emis <<<1024, 256, 0, stream>>>(h_f, h_b, Wout, bout, emis, (float*)d_out);
  k4_crf  <<<256, 128, 0, stream>>>(words, tags, emis, trans, st, et, (float*)d_out);
}

// Round 5
// 610.376 us; speedup vs baseline: 1.3603x; 1.3603x over previous
//
#include <hip/hip_runtime.h>
#include <hip/hip_bf16.h>

// Sizes (fixed by the reference)
//  V=32000, T=48, E=128, HID=256, H=128, B=256, L=512, 4H=512
typedef unsigned short ushort_t;
typedef unsigned int uint_t;
typedef __bf16 bf16x8 __attribute__((ext_vector_type(8)));
typedef float f32x4 __attribute__((ext_vector_type(4)));
typedef float f32x16 __attribute__((ext_vector_type(16)));

#define L2E 1.44269504088896340736f
#define LN2 0.69314718055994530942f

// LDS-only barrier: does NOT drain vmcnt -> global loads/stores stay in flight.
#define WGBAR() __asm__ volatile("s_waitcnt lgkmcnt(0)\n\ts_barrier" ::: "memory")

static __device__ __forceinline__ float fexp2(float x) { return __builtin_amdgcn_exp2f(x); }
static __device__ __forceinline__ float flog2(float x) { return __builtin_amdgcn_logf(x); }
static __device__ __forceinline__ float frcp (float x) { return __builtin_amdgcn_rcpf(x); }

static __device__ __forceinline__ float sigm(float x) {
  return frcp(1.0f + fexp2(-L2E * x));
}
static __device__ __forceinline__ float tanha(float x) {
  return 1.0f - 2.0f * frcp(1.0f + fexp2(2.0f * L2E * x));
}

static __device__ __forceinline__ ushort_t f2bf(float f) {
  union { float f; uint_t u; } v; v.f = f;
  uint_t u = v.u;
  uint_t r = (u + 0x7fffu + ((u >> 16) & 1u)) >> 16;  // RNE
  return (ushort_t)r;
}
static __device__ __forceinline__ bf16x8 pack8(float4 a, float4 b) {
  uint4 u = make_uint4(
      (uint_t)f2bf(a.x) | ((uint_t)f2bf(a.y) << 16),
      (uint_t)f2bf(a.z) | ((uint_t)f2bf(a.w) << 16),
      (uint_t)f2bf(b.x) | ((uint_t)f2bf(b.y) << 16),
      (uint_t)f2bf(b.z) | ((uint_t)f2bf(b.w) << 16));
  return __builtin_bit_cast(bf16x8, u);
}
static __device__ __forceinline__ bf16x8 zero8() {
  uint4 z = make_uint4(0u, 0u, 0u, 0u);
  return __builtin_bit_cast(bf16x8, z);
}
static __device__ __forceinline__ uint2 pack4(float4 a) {
  return make_uint2((uint_t)f2bf(a.x) | ((uint_t)f2bf(a.y) << 16),
                    (uint_t)f2bf(a.z) | ((uint_t)f2bf(a.w) << 16));
}

// DPP row-rotate-right by K within 16-lane rows (K=0 -> identity).
template <int K>
static __device__ __forceinline__ float rotk(float x) {
  if constexpr (K == 0) {
    return x;
  } else {
    return __builtin_bit_cast(float, __builtin_amdgcn_update_dpp(
        0, __builtin_bit_cast(int, x), 0x120 + K, 0xf, 0xf, true));
  }
}

// ---------------------------------------------------------------------------
// K2 v8 (unchanged): fully-fused BiLSTM. grid = 256 WGs x 512 thr; wg>>7 =
// dir, (wg&127)*2 = 2 batch rows. Production-A hoist: xs[pcon] is stable for
// the whole 8-step block, so production A-fragments load once per block.
// ---------------------------------------------------------------------------
__global__ __launch_bounds__(512, 2) void k2_lstm(
    const int* __restrict__ words, const float* __restrict__ emb,
    const float* __restrict__ Wih_f, const float* __restrict__ Whh_f,
    const float* __restrict__ bih_f, const float* __restrict__ bhh_f,
    const float* __restrict__ Wih_b, const float* __restrict__ Whh_b,
    const float* __restrict__ bih_b, const float* __restrict__ bhh_b,
    ushort_t* __restrict__ h_f, ushort_t* __restrict__ h_b) {
  const int wg = blockIdx.x;
  const int dir = wg >> 7;
  const int r0 = (wg & 127) << 1;
  const float* Whh = dir ? Whh_b : Whh_f;
  const float* Wih = dir ? Wih_b : Wih_f;
  const float* bih = dir ? bih_b : bih_f;
  const float* bhh = dir ? bhh_b : bhh_f;
  ushort_t* hout = dir ? h_b : h_f;

  const int tid = threadIdx.x;
  const int w = tid >> 6;        // wave 0..7
  const int lane = tid & 63;
  const int l15 = lane & 15;
  const int kq = lane >> 4;      // 0..3

  __shared__ __align__(16) ushort_t hx[2][2][136];      //  1,088 B
  __shared__ __align__(16) ushort_t xp[2][16][128][4];  // 32,768 B
  __shared__ __align__(16) ushort_t xs[2][16][136];     //  8,704 B

  // ---- register-resident weight fragments (bf16), [quadrant][K-chunk] ----
  // B layout (16x16x32): col n = lane&15, k = (lane>>4)*8 + j
  bf16x8 wfh[4][4], wfx[4][4];
  float biasP[4];   // production bias for col w*16+l15, quadrant Q
#pragma unroll
  for (int Q = 0; Q < 4; ++Q) {
    const int n = Q * 128 + w * 16 + l15;
    biasP[Q] = bih[n] + bhh[n];
#pragma unroll
    for (int c = 0; c < 4; ++c) {
      const int k0 = c * 32 + kq * 8;
      const float* sh = Whh + n * 128 + k0;
      const float* sx = Wih + n * 128 + k0;
      wfh[Q][c] = pack8(*(const float4*)sh, *(const float4*)(sh + 4));
      wfx[Q][c] = pack8(*(const float4*)sx, *(const float4*)(sx + 4));
    }
  }

  const int ur = (lane >> 4) & 1;
  const int uj = w * 16 + l15;
  float cst = 0.f;

  // staging thread mapping: 512 thr cover 16 rows x 128 cols (4 floats each)
  const int sm = tid >> 5;          // xs row 0..15  (tl = sm>>1, r = sm&1)
  const int sc = (tid & 31) * 4;    // col 0..124
  const int str = r0 + (sm & 1);
  const int stl = sm >> 1;

  // production pack registers (live across the 4 Q sub-phases of a block)
  uint_t pd0[4], pd1[4];
  f32x4 pc = {0.f, 0.f, 0.f, 0.f};

  // ---- prologue ----
  if (tid < 256) hx[0][tid >> 7][tid & 127] = 0;   // h(-1) = 0
  {  // stage xs[1] = x(block 0)
    const int tg = stl;
    const int tf = dir ? (511 - tg) : tg;
    const int word = words[str * 512 + tf];
    float4 av = *(const float4*)(emb + (size_t)word * 128 + sc);
    *(uint2*)&xs[1][sm][sc] = pack4(av);
  }
  WGBAR();
  // produce xp[0] from xs[1] (16 dense MFMAs/wave), bias in C-init
#pragma unroll
  for (int Q = 0; Q < 4; ++Q) {
    f32x4 pc0 = {biasP[Q], biasP[Q], biasP[Q], biasP[Q]};
#pragma unroll
    for (int c = 0; c < 4; ++c) {
      bf16x8 af = __builtin_bit_cast(bf16x8, *(const uint4*)&xs[1][l15][kq * 8 + c * 32]);
      pc0 = __builtin_amdgcn_mfma_f32_16x16x32_bf16(af, wfx[Q][c], pc0, 0, 0, 0);
    }
#pragma unroll
    for (int rr = 0; rr < 4; ++rr) {
      const uint_t bb = (uint_t)f2bf(pc0[rr]);
      if (Q == 0) pd0[rr] = bb;
      else if (Q == 1) pd0[rr] |= bb << 16;
      else if (Q == 2) pd1[rr] = bb;
      else pd1[rr] |= bb << 16;
    }
  }
#pragma unroll
  for (int rr = 0; rr < 4; ++rr)
    *(uint2*)&xp[0][kq * 4 + rr][uj][0] = make_uint2(pd0[rr], pd1[rr]);
  {  // stage xs[0] = x(block 1)
    const int tg = 8 + stl;
    const int tf = dir ? (511 - tg) : tg;
    const int word = words[str * 512 + tf];
    float4 av = *(const float4*)(emb + (size_t)word * 128 + sc);
    *(uint2*)&xs[0][sm][sc] = pack4(av);
  }
  WGBAR();

  int sword = 0;
  float4 se0 = make_float4(0.f, 0.f, 0.f, 0.f);

#pragma unroll 1
  for (int i = 0; i < 64; ++i) {   // 64 blocks of 8 steps
    const int pcon = i & 1;        // consume xp[pcon]; production reads xs[pcon]
    const int ppro = pcon ^ 1;     // produce xp[ppro]; staging writes xs[ppro]
    // ---- per-block hoist: production A-fragments (xs[pcon] stable all block)
    bf16x8 afp[4];
    if (i < 63) {
#pragma unroll
      for (int c = 0; c < 4; ++c)
        afp[c] = __builtin_bit_cast(bf16x8, *(const uint4*)&xs[pcon][l15][kq * 8 + c * 32]);
    }
#pragma unroll
    for (int s = 0; s < 8; ++s) {
      const int t = i * 8 + s;
      const int p = t & 1;
      // xp consumption: one b64 read (Q0..Q3 packed for this lane's (ur,uj))
      const uint2 xq = *(const uint2*)&xp[pcon][2 * s + ur][uj][0];
      // staging pipeline for x(block i+2): word @s0, emb @s2, LDS write @s6
      if (i < 62) {
        if (s == 0) {
          const int tg = (i + 2) * 8 + stl;
          const int tf = dir ? (511 - tg) : tg;
          sword = words[str * 512 + tf];
        }
        if (s == 2) se0 = *(const float4*)(emb + (size_t)sword * 128 + sc);
        if (s == 6) *(uint2*)&xs[ppro][sm][sc] = pack4(se0);
      }
      // ---- recurrence MFMAs: gates_h = h @ Whh^T (K=128) ----
      f32x4 a0 = {0.f, 0.f, 0.f, 0.f}, a1 = a0, a2 = a0, a3 = a0;
      const ushort_t* abase = &hx[p][l15 & 1][kq * 8];
#pragma unroll
      for (int c = 0; c < 4; ++c) {
        bf16x8 af = __builtin_bit_cast(bf16x8, *(const uint4*)(abase + c * 32));
        a0 = __builtin_amdgcn_mfma_f32_16x16x32_bf16(af, wfh[0][c], a0, 0, 0, 0);
        a1 = __builtin_amdgcn_mfma_f32_16x16x32_bf16(af, wfh[1][c], a1, 0, 0, 0);
        a2 = __builtin_amdgcn_mfma_f32_16x16x32_bf16(af, wfh[2][c], a2, 0, 0, 0);
        a3 = __builtin_amdgcn_mfma_f32_16x16x32_bf16(af, wfh[3][c], a3, 0, 0, 0);
      }
      // ---- production MFMAs for block i+1 (independent; fills bubbles).
      //      A-fragments from afp regs; results buffered in pd0/pd1;
      //      single 4x b64 LDS write at s==7.
      if (i < 63) {
        const int Q = s >> 1;
        if ((s & 1) == 0) {
          pc = f32x4{biasP[Q], biasP[Q], biasP[Q], biasP[Q]};
          pc = __builtin_amdgcn_mfma_f32_16x16x32_bf16(afp[0], wfx[Q][0], pc, 0, 0, 0);
          pc = __builtin_amdgcn_mfma_f32_16x16x32_bf16(afp[1], wfx[Q][1], pc, 0, 0, 0);
        } else {
          pc = __builtin_amdgcn_mfma_f32_16x16x32_bf16(afp[2], wfx[Q][2], pc, 0, 0, 0);
          pc = __builtin_amdgcn_mfma_f32_16x16x32_bf16(afp[3], wfx[Q][3], pc, 0, 0, 0);
#pragma unroll
          for (int rr = 0; rr < 4; ++rr) {
            const uint_t bb = (uint_t)f2bf(pc[rr]);
            if (Q == 0) pd0[rr] = bb;
            else if (Q == 1) pd0[rr] |= bb << 16;
            else if (Q == 2) pd1[rr] = bb;
            else pd1[rr] |= bb << 16;
          }
          if (s == 7) {
#pragma unroll
            for (int rr = 0; rr < 4; ++rr)
              *(uint2*)&xp[ppro][kq * 4 + rr][uj][0] = make_uint2(pd0[rr], pd1[rr]);
          }
        }
      }
      // ---- gates: lane's own (ur,uj) pair -- reg[0]=batch0, reg[1]=batch1
      const float g0 = (ur ? a0[1] : a0[0]) + __builtin_bit_cast(float, xq.x << 16);
      const float g1 = (ur ? a1[1] : a1[0]) + __builtin_bit_cast(float, xq.x & 0xffff0000u);
      const float g2 = (ur ? a2[1] : a2[0]) + __builtin_bit_cast(float, xq.y << 16);
      const float g3 = (ur ? a3[1] : a3[0]) + __builtin_bit_cast(float, xq.y & 0xffff0000u);
      // activations (one chain per lane; lanes>=32 duplicate, stores guarded)
      const float si = sigm(g0), sf = sigm(g1), so = sigm(g3);
      const float tg = tanha(g2);
      cst = sf * cst + si * tg;
      const float h = so * tanha(cst);
      const ushort_t hb = f2bf(h);
      if (lane < 32) {
        hx[p ^ 1][ur][uj] = hb;
        const int tf = dir ? (511 - t) : t;
        hout[(tf * 256 + r0 + ur) * 128 + uj] = hb;  // stays in flight
      }
      WGBAR();
    }
  }
}

// ---------------------------------------------------------------------------
// K3: emis[t*256+b][48] = [h_f|h_b] @ Wout^T + bout  (fp32 out)
// Also zeroes the loss accumulator (block 0, thread 0) so K4 can atomicAdd.
// ---------------------------------------------------------------------------
__global__ __launch_bounds__(256, 2) void k3_emis(
    const ushort_t* __restrict__ h_f, const ushort_t* __restrict__ h_b,
    const float* __restrict__ Wout, const float* __restrict__ bout,
    float* __restrict__ emis, float* __restrict__ loss_out) {
  if (blockIdx.x == 0 && threadIdx.x == 0) loss_out[0] = 0.f;
  const int w = threadIdx.x >> 6;
  const int lane = threadIdx.x & 63;
  const int m31 = lane & 31;
  const int q = lane >> 5;
  const int Mbase = blockIdx.x * 128 + w * 32;

  bf16x8 bfr[2][16];
  float bo[2];
#pragma unroll
  for (int T = 0; T < 2; ++T) {
    const int n = T * 32 + m31;
    if (n < 48) {
      bo[T] = bout[n];
#pragma unroll
      for (int c = 0; c < 16; ++c) {
        const float* src = Wout + n * 256 + c * 16 + q * 8;
        bfr[T][c] = pack8(*(const float4*)src, *(const float4*)(src + 4));
      }
    } else {
      bo[T] = 0.f;
#pragma unroll
      for (int c = 0; c < 16; ++c) bfr[T][c] = zero8();
    }
  }
  f32x16 acc0{}, acc1{};
  const ushort_t* hrf = h_f + (long)(Mbase + m31) * 128;
  const ushort_t* hrb = h_b + (long)(Mbase + m31) * 128;
#pragma unroll
  for (int c = 0; c < 16; ++c) {
    const ushort_t* src = (c < 8) ? (hrf + c * 16 + q * 8) : (hrb + (c - 8) * 16 + q * 8);
    bf16x8 af = __builtin_bit_cast(bf16x8, *(const uint4*)src);
    acc0 = __builtin_amdgcn_mfma_f32_32x32x16_bf16(af, bfr[0][c], acc0, 0, 0, 0);
    acc1 = __builtin_amdgcn_mfma_f32_32x32x16_bf16(af, bfr[1][c], acc1, 0, 0, 0);
  }
#pragma unroll
  for (int T = 0; T < 2; ++T) {
    const int n = T * 32 + m31;
    if (n >= 48) continue;
    f32x16 A = T ? acc1 : acc0;
#pragma unroll
    for (int r = 0; r < 16; ++r) {
      const int row = (r & 3) + ((r >> 2) << 3) + (q << 2);
      emis[(long)(Mbase + row) * 48 + n] = A[r] + bo[T];
    }
  }
}

// ---------------------------------------------------------------------------
// K4 v8: identical to v7 EXCEPT __launch_bounds__(128, 1). v7's register
// all-gather needs pcr[64] + mb[16] + state ~ 110+ VGPRs; the default
// allocator capped at 64 (round-4 counters: VGPR_Count=64, VALUBusy 5.6%)
// and spilled the coefficient array to scratch -- every FMA on the 512-step
// serial chain waited a scratch load. launch_bounds(128,1) lifts the cap so
// pcr stays register-resident. 256 WGs x 128 thr.
// ---------------------------------------------------------------------------
#define K4_ROW(OP, m) \
  OP(m, 0) OP(m, 1) OP(m, 2) OP(m, 3) OP(m, 4) OP(m, 5) OP(m, 6) OP(m, 7) \
  OP(m, 8) OP(m, 9) OP(m, 10) OP(m, 11) OP(m, 12) OP(m, 13) OP(m, 14) OP(m, 15)
#define K4_ALL(OP) K4_ROW(OP, 0) K4_ROW(OP, 1) K4_ROW(OP, 2) K4_ROW(OP, 3)

__global__ __launch_bounds__(128, 1) void k4_crf(
    const int* __restrict__ words, const int* __restrict__ tags,
    const float* __restrict__ emis, const float* __restrict__ trans,
    const float* __restrict__ st, const float* __restrict__ et,
    float* __restrict__ out) {
  const int b = blockIdx.x;
  const int tid = threadIdx.x;
  const int j = tid & 63;
  __shared__ float res[2];

  if (tid >= 64) {
    // ---- wave 1: numerator (gold path score) ----
    float s = 0.f;
    int cnt = 0;
#pragma unroll 1
    for (int s8 = 0; s8 < 8; ++s8) {
      const int t = j + (s8 << 6);
      const int wv = words[b * 512 + t];
      const int tg = tags[b * 512 + t];
      const bool mt = (wv != 0);
      cnt += mt ? 1 : 0;
      if (t == 0) {
        s += st[tg] + emis[b * 48 + tg];
      } else if (mt) {
        const int tp = tags[b * 512 + t - 1];
        s += trans[tp * 48 + tg] + emis[(t * 256 + b) * 48 + tg];
      }
    }
#pragma unroll
    for (int d = 32; d; d >>= 1) {
      s += __shfl_xor(s, d, 64);
      cnt += __shfl_xor(cnt, d, 64);
    }
    if (j == 0) {
      const int lt = tags[b * 512 + cnt - 1];
      res[1] = s + et[lt];
    }
  } else {
    // ---- wave 0: denominator, forward algorithm in linear domain ----
    const bool v = j < 48;

    // self-calibration: discover source index of each (m,k) gather slot
    float pcr[64];
    {
      float pm[4];
      const float pj = (float)j;
      pm[0] = pj;
      pm[1] = __shfl_xor(pj, 16, 64);
      pm[2] = __shfl_xor(pj, 32, 64);
      pm[3] = __shfl_xor(pj, 48, 64);
#define K4_CAL(m, k) { const int idx_ = (int)rotk<k>(pm[m]); \
      pcr[(m) * 16 + (k)] = (v && idx_ < 48) ? fexp2(trans[idx_ * 48 + j] * L2E) : 0.f; }
      K4_ALL(K4_CAL)
#undef K4_CAL
    }

    // mask bits: mb[q] bit s = (words[b*512 + q*64 + s] != 0)
    unsigned long long mb[8];
#pragma unroll
    for (int q = 0; q < 8; ++q)
      mb[q] = __ballot(words[b * 512 + q * 64 + j] != 0);

    float d = v ? fexp2((st[j] + emis[b * 48 + j]) * L2E) : 0.f;
    int S = 0, e_pend = 0;

    float em0 = v ? emis[(1 * 256 + b) * 48 + j] : 0.f;
    float em1 = v ? emis[(2 * 256 + b) * 48 + j] : 0.f;
    float em2 = v ? emis[(3 * 256 + b) * 48 + j] : 0.f;
    float em3 = v ? emis[(4 * 256 + b) * 48 + j] : 0.f;
    float Ecur = fexp2(em0 * L2E);

#pragma unroll 1
    for (int q = 0; q < 8; ++q) {
      const unsigned long long m = mb[q];
      const int s0 = (q == 0) ? 1 : 0;
#pragma unroll 1
      for (int s = s0; s < 64; ++s) {
        const int t = q * 64 + s;
        float E = Ecur;
        int eApp = 0;
        if ((s & 7) == 2) {   // fold lagged renorm into E (uniform branch)
          const float sc = __builtin_bit_cast(float, (uint_t)(127 - e_pend) << 23);
          E *= sc;
          eApp = e_pend;
        }
        const int tn = min(511, t + 4);
        em0 = em1; em1 = em2; em2 = em3;
        em3 = v ? emis[(tn * 256 + b) * 48 + j] : 0.f;  // vmcnt path, depth-4
        const float En = fexp2(em0 * L2E);              // E for t+1, off-chain

        // register all-gather matvec: nxt_j = sum_i d_i * P[i][j]
        float dm[4];
        dm[0] = d;
        dm[1] = __shfl_xor(d, 16, 64);
        dm[2] = __shfl_xor(d, 32, 64);
        dm[3] = __shfl_xor(d, 48, 64);
        float acc[8] = {0.f, 0.f, 0.f, 0.f, 0.f, 0.f, 0.f, 0.f};
#define K4_FMA(m, k) acc[((m) * 16 + (k)) & 7] = \
        fmaf(rotk<k>(dm[m]), pcr[(m) * 16 + (k)], acc[((m) * 16 + (k)) & 7]);
        K4_ALL(K4_FMA)
#undef K4_FMA
        const float nxt = (((acc[0] + acc[1]) + (acc[2] + acc[3])) +
                           ((acc[4] + acc[5]) + (acc[6] + acc[7]))) * E;
        if ((m >> s) & 1ull) {   // wave-uniform scalar branch, no memory
          d = v ? nxt : 0.f;
          S += eApp;
        }
        if ((s & 7) == 0) {      // lagged exponent measurement (any lane works)
          const int db = __builtin_amdgcn_readfirstlane(__builtin_bit_cast(int, d));
          e_pend = ((db >> 23) & 0xff) - 127;
        }
        Ecur = En;
      }
    }
    float uf = v ? d * fexp2(et[j] * L2E) : 0.f;
#pragma unroll
    for (int dd = 32; dd; dd >>= 1) uf += __shfl_xor(uf, dd, 64);
    if (j == 0) res[0] = ((float)S + flog2(uf)) * LN2;
  }
  __syncthreads();
  // loss = -mean(num - denom)  ->  accumulate (denom - num)/256
  if (tid == 0) atomicAdd(out, (res[0] - res[1]) * (1.0f / 256.0f));
}

// ---------------------------------------------------------------------------
extern "C" void kernel_launch(void* const* d_in, const int* in_sizes, int n_in,
                              void* d_out, int out_size, void* d_ws, size_t ws_size,
                              hipStream_t stream) {
  (void)in_sizes; (void)n_in; (void)out_size; (void)ws_size;
  const int*   words = (const int*)d_in[0];
  const int*   tags  = (const int*)d_in[1];
  // d_in[2] = mask (bool) -- unused; reconstructed as words != 0
  const float* emb   = (const float*)d_in[3];
  const float* Wih_f = (const float*)d_in[4];
  const float* Whh_f = (const float*)d_in[5];
  const float* bih_f = (const float*)d_in[6];
  const float* bhh_f = (const float*)d_in[7];
  const float* Wih_b = (const float*)d_in[8];
  const float* Whh_b = (const float*)d_in[9];
  const float* bih_b = (const float*)d_in[10];
  const float* bhh_b = (const float*)d_in[11];
  const float* Wout  = (const float*)d_in[12];
  const float* bout  = (const float*)d_in[13];
  const float* trans = (const float*)d_in[14];
  const float* st    = (const float*)d_in[15];
  const float* et    = (const float*)d_in[16];

  char* ws = (char*)d_ws;
  ushort_t* h_f   = (ushort_t*)(ws);                    // 33,554,432 B
  ushort_t* h_b   = (ushort_t*)(ws + 33554432);         // 33,554,432 B
  float*    emis  = (float*)   (ws + 67108864);         // 25,165,824 B
  // total ws needed: ~92.3 MB (within the known-good 125.8 MB envelope)

  k2_lstm <<<256, 512, 0, stream>>>(words, emb,
                                    Wih_f, Whh_f, bih_f, bhh_f,
                                    Wih_b, Whh_b, bih_b, bhh_b,
                                    h_f, h_b);
  k3_emis <<<1024, 256, 0, stream>>>(h_f, h_b, Wout, bout, emis, (float*)d_out);
  k4_crf  <<<256, 128, 0, stream>>>(words, tags, emis, trans, st, et, (float*)d_out);
}

// Round 6
// 577.321 us; speedup vs baseline: 1.4382x; 1.0573x over previous
//
#include <hip/hip_runtime.h>
#include <hip/hip_bf16.h>

// Sizes (fixed by the reference)
//  V=32000, T=48, E=128, HID=256, H=128, B=256, L=512, 4H=512
typedef unsigned short ushort_t;
typedef unsigned int uint_t;
typedef __bf16 bf16x8 __attribute__((ext_vector_type(8)));
typedef float f32x4 __attribute__((ext_vector_type(4)));
typedef float f32x16 __attribute__((ext_vector_type(16)));

#define L2E 1.44269504088896340736f
#define LN2 0.69314718055994530942f

// LDS-only barrier: does NOT drain vmcnt -> global loads/stores stay in flight.
#define WGBAR() __asm__ volatile("s_waitcnt lgkmcnt(0)\n\ts_barrier" ::: "memory")

static __device__ __forceinline__ float fexp2(float x) { return __builtin_amdgcn_exp2f(x); }
static __device__ __forceinline__ float flog2(float x) { return __builtin_amdgcn_logf(x); }
static __device__ __forceinline__ float frcp (float x) { return __builtin_amdgcn_rcpf(x); }

static __device__ __forceinline__ float sigm(float x) {
  return frcp(1.0f + fexp2(-L2E * x));
}
static __device__ __forceinline__ float tanha(float x) {
  return 1.0f - 2.0f * frcp(1.0f + fexp2(2.0f * L2E * x));
}

// Hardware bf16 pair-convert (RNE -- bit-identical to the previous software
// round-to-nearest-even). result = bf16(lo) | bf16(hi)<<16, one VALU instr.
static __device__ __forceinline__ uint_t cvtpk(float lo, float hi) {
  uint_t r;
  asm("v_cvt_pk_bf16_f32 %0, %1, %2" : "=v"(r) : "v"(lo), "v"(hi));
  return r;
}
static __device__ __forceinline__ bf16x8 pack8(float4 a, float4 b) {
  uint4 u = make_uint4(cvtpk(a.x, a.y), cvtpk(a.z, a.w),
                       cvtpk(b.x, b.y), cvtpk(b.z, b.w));
  return __builtin_bit_cast(bf16x8, u);
}
static __device__ __forceinline__ bf16x8 zero8() {
  uint4 z = make_uint4(0u, 0u, 0u, 0u);
  return __builtin_bit_cast(bf16x8, z);
}
static __device__ __forceinline__ uint2 pack4(float4 a) {
  return make_uint2(cvtpk(a.x, a.y), cvtpk(a.z, a.w));
}

// DPP row-rotate-right by K within 16-lane rows (K=0 -> identity).
template <int K>
static __device__ __forceinline__ float rotk(float x) {
  if constexpr (K == 0) {
    return x;
  } else {
    return __builtin_bit_cast(float, __builtin_amdgcn_update_dpp(
        0, __builtin_bit_cast(int, x), 0x120 + K, 0xf, 0xf, true));
  }
}

// ---------------------------------------------------------------------------
// K2 v9: fully-fused BiLSTM. v8 structure + VALU-issue cuts (k2 is ~80%
// combined-pipe-busy per round-5 counters -> instruction count is the lever):
//  - persistent fz zero quad as MFMA C-init (removes 16 v_mov/wave/step)
//  - v_cvt_pk_bf16_f32 for all f32->bf16 packing (xp production pairs,
//    h value, staging pack4): 1 instr per pair vs ~4-op software RNE.
// ---------------------------------------------------------------------------
__global__ __launch_bounds__(512, 2) void k2_lstm(
    const int* __restrict__ words, const float* __restrict__ emb,
    const float* __restrict__ Wih_f, const float* __restrict__ Whh_f,
    const float* __restrict__ bih_f, const float* __restrict__ bhh_f,
    const float* __restrict__ Wih_b, const float* __restrict__ Whh_b,
    const float* __restrict__ bih_b, const float* __restrict__ bhh_b,
    ushort_t* __restrict__ h_f, ushort_t* __restrict__ h_b) {
  const int wg = blockIdx.x;
  const int dir = wg >> 7;
  const int r0 = (wg & 127) << 1;
  const float* Whh = dir ? Whh_b : Whh_f;
  const float* Wih = dir ? Wih_b : Wih_f;
  const float* bih = dir ? bih_b : bih_f;
  const float* bhh = dir ? bhh_b : bhh_f;
  ushort_t* hout = dir ? h_b : h_f;

  const int tid = threadIdx.x;
  const int w = tid >> 6;        // wave 0..7
  const int lane = tid & 63;
  const int l15 = lane & 15;
  const int kq = lane >> 4;      // 0..3

  __shared__ __align__(16) ushort_t hx[2][2][136];      //  1,088 B
  __shared__ __align__(16) ushort_t xp[2][16][128][4];  // 32,768 B
  __shared__ __align__(16) ushort_t xs[2][16][136];     //  8,704 B

  // ---- register-resident weight fragments (bf16), [quadrant][K-chunk] ----
  // B layout (16x16x32): col n = lane&15, k = (lane>>4)*8 + j
  bf16x8 wfh[4][4], wfx[4][4];
  float biasP[4];   // production bias for col w*16+l15, quadrant Q
#pragma unroll
  for (int Q = 0; Q < 4; ++Q) {
    const int n = Q * 128 + w * 16 + l15;
    biasP[Q] = bih[n] + bhh[n];
#pragma unroll
    for (int c = 0; c < 4; ++c) {
      const int k0 = c * 32 + kq * 8;
      const float* sh = Whh + n * 128 + k0;
      const float* sx = Wih + n * 128 + k0;
      wfh[Q][c] = pack8(*(const float4*)sh, *(const float4*)(sh + 4));
      wfx[Q][c] = pack8(*(const float4*)sx, *(const float4*)(sx + 4));
    }
  }

  const int ur = (lane >> 4) & 1;
  const int uj = w * 16 + l15;
  float cst = 0.f;
  const f32x4 fz = {0.f, 0.f, 0.f, 0.f};   // persistent MFMA C-init

  // staging thread mapping: 512 thr cover 16 rows x 128 cols (4 floats each)
  const int sm = tid >> 5;          // xs row 0..15  (tl = sm>>1, r = sm&1)
  const int sc = (tid & 31) * 4;    // col 0..124
  const int str = r0 + (sm & 1);
  const int stl = sm >> 1;

  // production pack registers (live across the 4 Q sub-phases of a block)
  uint_t pd0[4], pd1[4];
  f32x4 pc = {0.f, 0.f, 0.f, 0.f};
  f32x4 pcsv = {0.f, 0.f, 0.f, 0.f};

  // ---- prologue ----
  if (tid < 256) hx[0][tid >> 7][tid & 127] = 0;   // h(-1) = 0
  {  // stage xs[1] = x(block 0)
    const int tg = stl;
    const int tf = dir ? (511 - tg) : tg;
    const int word = words[str * 512 + tf];
    float4 av = *(const float4*)(emb + (size_t)word * 128 + sc);
    *(uint2*)&xs[1][sm][sc] = pack4(av);
  }
  WGBAR();
  // produce xp[0] from xs[1] (16 dense MFMAs/wave), bias in C-init
  {
    f32x4 qv[4];
#pragma unroll
    for (int Q = 0; Q < 4; ++Q) {
      f32x4 pc0 = {biasP[Q], biasP[Q], biasP[Q], biasP[Q]};
#pragma unroll
      for (int c = 0; c < 4; ++c) {
        bf16x8 af = __builtin_bit_cast(bf16x8, *(const uint4*)&xs[1][l15][kq * 8 + c * 32]);
        pc0 = __builtin_amdgcn_mfma_f32_16x16x32_bf16(af, wfx[Q][c], pc0, 0, 0, 0);
      }
      qv[Q] = pc0;
    }
#pragma unroll
    for (int rr = 0; rr < 4; ++rr) {
      pd0[rr] = cvtpk(qv[0][rr], qv[1][rr]);
      pd1[rr] = cvtpk(qv[2][rr], qv[3][rr]);
      *(uint2*)&xp[0][kq * 4 + rr][uj][0] = make_uint2(pd0[rr], pd1[rr]);
    }
  }
  {  // stage xs[0] = x(block 1)
    const int tg = 8 + stl;
    const int tf = dir ? (511 - tg) : tg;
    const int word = words[str * 512 + tf];
    float4 av = *(const float4*)(emb + (size_t)word * 128 + sc);
    *(uint2*)&xs[0][sm][sc] = pack4(av);
  }
  WGBAR();

  int sword = 0;
  float4 se0 = make_float4(0.f, 0.f, 0.f, 0.f);

#pragma unroll 1
  for (int i = 0; i < 64; ++i) {   // 64 blocks of 8 steps
    const int pcon = i & 1;        // consume xp[pcon]; production reads xs[pcon]
    const int ppro = pcon ^ 1;     // produce xp[ppro]; staging writes xs[ppro]
    // ---- per-block hoist: production A-fragments (xs[pcon] stable all block)
    bf16x8 afp[4];
    if (i < 63) {
#pragma unroll
      for (int c = 0; c < 4; ++c)
        afp[c] = __builtin_bit_cast(bf16x8, *(const uint4*)&xs[pcon][l15][kq * 8 + c * 32]);
    }
#pragma unroll
    for (int s = 0; s < 8; ++s) {
      const int t = i * 8 + s;
      const int p = t & 1;
      // xp consumption: one b64 read (Q0..Q3 packed for this lane's (ur,uj))
      const uint2 xq = *(const uint2*)&xp[pcon][2 * s + ur][uj][0];
      // staging pipeline for x(block i+2): word @s0, emb @s2, LDS write @s6
      if (i < 62) {
        if (s == 0) {
          const int tg = (i + 2) * 8 + stl;
          const int tf = dir ? (511 - tg) : tg;
          sword = words[str * 512 + tf];
        }
        if (s == 2) se0 = *(const float4*)(emb + (size_t)sword * 128 + sc);
        if (s == 6) *(uint2*)&xs[ppro][sm][sc] = pack4(se0);
      }
      // ---- recurrence MFMAs: gates_h = h @ Whh^T (K=128); C-init = fz ----
      f32x4 a0, a1, a2, a3;
      const ushort_t* abase = &hx[p][l15 & 1][kq * 8];
      {
        bf16x8 af = __builtin_bit_cast(bf16x8, *(const uint4*)(abase));
        a0 = __builtin_amdgcn_mfma_f32_16x16x32_bf16(af, wfh[0][0], fz, 0, 0, 0);
        a1 = __builtin_amdgcn_mfma_f32_16x16x32_bf16(af, wfh[1][0], fz, 0, 0, 0);
        a2 = __builtin_amdgcn_mfma_f32_16x16x32_bf16(af, wfh[2][0], fz, 0, 0, 0);
        a3 = __builtin_amdgcn_mfma_f32_16x16x32_bf16(af, wfh[3][0], fz, 0, 0, 0);
      }
#pragma unroll
      for (int c = 1; c < 4; ++c) {
        bf16x8 af = __builtin_bit_cast(bf16x8, *(const uint4*)(abase + c * 32));
        a0 = __builtin_amdgcn_mfma_f32_16x16x32_bf16(af, wfh[0][c], a0, 0, 0, 0);
        a1 = __builtin_amdgcn_mfma_f32_16x16x32_bf16(af, wfh[1][c], a1, 0, 0, 0);
        a2 = __builtin_amdgcn_mfma_f32_16x16x32_bf16(af, wfh[2][c], a2, 0, 0, 0);
        a3 = __builtin_amdgcn_mfma_f32_16x16x32_bf16(af, wfh[3][c], a3, 0, 0, 0);
      }
      // ---- production MFMAs for block i+1 (independent; fills bubbles).
      //      Q results packed in PAIRS via v_cvt_pk_bf16_f32 (pcsv holds the
      //      even-Q result until the odd Q completes); single write at s==7.
      if (i < 63) {
        const int Q = s >> 1;
        if ((s & 1) == 0) {
          pc = f32x4{biasP[Q], biasP[Q], biasP[Q], biasP[Q]};
          pc = __builtin_amdgcn_mfma_f32_16x16x32_bf16(afp[0], wfx[Q][0], pc, 0, 0, 0);
          pc = __builtin_amdgcn_mfma_f32_16x16x32_bf16(afp[1], wfx[Q][1], pc, 0, 0, 0);
        } else {
          pc = __builtin_amdgcn_mfma_f32_16x16x32_bf16(afp[2], wfx[Q][2], pc, 0, 0, 0);
          pc = __builtin_amdgcn_mfma_f32_16x16x32_bf16(afp[3], wfx[Q][3], pc, 0, 0, 0);
          if ((s & 2) == 0) {          // s==1 (Q0) or s==5 (Q2): save
            pcsv = pc;
          } else if (s == 3) {         // Q1 done: pd0 = pack(Q0, Q1)
#pragma unroll
            for (int rr = 0; rr < 4; ++rr) pd0[rr] = cvtpk(pcsv[rr], pc[rr]);
          } else {                     // s==7, Q3: pd1 = pack(Q2, Q3) + write
#pragma unroll
            for (int rr = 0; rr < 4; ++rr) {
              pd1[rr] = cvtpk(pcsv[rr], pc[rr]);
              *(uint2*)&xp[ppro][kq * 4 + rr][uj][0] = make_uint2(pd0[rr], pd1[rr]);
            }
          }
        }
      }
      // ---- gates: lane's own (ur,uj) pair -- reg[0]=batch0, reg[1]=batch1
      const float g0 = (ur ? a0[1] : a0[0]) + __builtin_bit_cast(float, xq.x << 16);
      const float g1 = (ur ? a1[1] : a1[0]) + __builtin_bit_cast(float, xq.x & 0xffff0000u);
      const float g2 = (ur ? a2[1] : a2[0]) + __builtin_bit_cast(float, xq.y << 16);
      const float g3 = (ur ? a3[1] : a3[0]) + __builtin_bit_cast(float, xq.y & 0xffff0000u);
      // activations (one chain per lane; lanes>=32 duplicate, stores guarded)
      const float si = sigm(g0), sf = sigm(g1), so = sigm(g3);
      const float tg = tanha(g2);
      cst = sf * cst + si * tg;
      const float h = so * tanha(cst);
      const ushort_t hb = (ushort_t)cvtpk(h, h);
      if (lane < 32) {
        hx[p ^ 1][ur][uj] = hb;
        const int tf = dir ? (511 - t) : t;
        hout[(tf * 256 + r0 + ur) * 128 + uj] = hb;  // stays in flight
      }
      WGBAR();
    }
  }
}

// ---------------------------------------------------------------------------
// K3: emis[t*256+b][48] = [h_f|h_b] @ Wout^T + bout  (fp32 out)
// Also zeroes the loss accumulator (block 0, thread 0) so K4 can atomicAdd.
// ---------------------------------------------------------------------------
__global__ __launch_bounds__(256, 2) void k3_emis(
    const ushort_t* __restrict__ h_f, const ushort_t* __restrict__ h_b,
    const float* __restrict__ Wout, const float* __restrict__ bout,
    float* __restrict__ emis, float* __restrict__ loss_out) {
  if (blockIdx.x == 0 && threadIdx.x == 0) loss_out[0] = 0.f;
  const int w = threadIdx.x >> 6;
  const int lane = threadIdx.x & 63;
  const int m31 = lane & 31;
  const int q = lane >> 5;
  const int Mbase = blockIdx.x * 128 + w * 32;

  bf16x8 bfr[2][16];
  float bo[2];
#pragma unroll
  for (int T = 0; T < 2; ++T) {
    const int n = T * 32 + m31;
    if (n < 48) {
      bo[T] = bout[n];
#pragma unroll
      for (int c = 0; c < 16; ++c) {
        const float* src = Wout + n * 256 + c * 16 + q * 8;
        bfr[T][c] = pack8(*(const float4*)src, *(const float4*)(src + 4));
      }
    } else {
      bo[T] = 0.f;
#pragma unroll
      for (int c = 0; c < 16; ++c) bfr[T][c] = zero8();
    }
  }
  f32x16 acc0{}, acc1{};
  const ushort_t* hrf = h_f + (long)(Mbase + m31) * 128;
  const ushort_t* hrb = h_b + (long)(Mbase + m31) * 128;
#pragma unroll
  for (int c = 0; c < 16; ++c) {
    const ushort_t* src = (c < 8) ? (hrf + c * 16 + q * 8) : (hrb + (c - 8) * 16 + q * 8);
    bf16x8 af = __builtin_bit_cast(bf16x8, *(const uint4*)src);
    acc0 = __builtin_amdgcn_mfma_f32_32x32x16_bf16(af, bfr[0][c], acc0, 0, 0, 0);
    acc1 = __builtin_amdgcn_mfma_f32_32x32x16_bf16(af, bfr[1][c], acc1, 0, 0, 0);
  }
#pragma unroll
  for (int T = 0; T < 2; ++T) {
    const int n = T * 32 + m31;
    if (n >= 48) continue;
    f32x16 A = T ? acc1 : acc0;
#pragma unroll
    for (int r = 0; r < 16; ++r) {
      const int row = (r & 3) + ((r >> 2) << 3) + (q << 2);
      emis[(long)(Mbase + row) * 48 + n] = A[r] + bo[T];
    }
  }
}

// ---------------------------------------------------------------------------
// K4 v9: fused CRF, register-gather matvec with HAND-FUSED v_fmac_f32_dpp.
// Round-5 chain was ~806 cy/step vs ~300 modeled; prime suspect is the
// compiler NOT fusing v_mov_b32_dpp + v_fma (64 extra instrs + dep stalls,
// fully exposed at 1 wave/SIMD). The inline asm guarantees the fused form:
// one v_fmac_f32 with row_ror:K on src0 per slot. The calibration uses the
// SAME row_ror:K control (0x120+K) so the permutation stays semantics-proof.
// ---------------------------------------------------------------------------
#define K4_ROW(OP, m) \
  OP(m, 0) OP(m, 1) OP(m, 2) OP(m, 3) OP(m, 4) OP(m, 5) OP(m, 6) OP(m, 7) \
  OP(m, 8) OP(m, 9) OP(m, 10) OP(m, 11) OP(m, 12) OP(m, 13) OP(m, 14) OP(m, 15)
#define K4_ALL(OP) K4_ROW(OP, 0) K4_ROW(OP, 1) K4_ROW(OP, 2) K4_ROW(OP, 3)

#define ROTMOD_0  ""
#define ROTMOD_1  "row_ror:1 row_mask:0xf bank_mask:0xf"
#define ROTMOD_2  "row_ror:2 row_mask:0xf bank_mask:0xf"
#define ROTMOD_3  "row_ror:3 row_mask:0xf bank_mask:0xf"
#define ROTMOD_4  "row_ror:4 row_mask:0xf bank_mask:0xf"
#define ROTMOD_5  "row_ror:5 row_mask:0xf bank_mask:0xf"
#define ROTMOD_6  "row_ror:6 row_mask:0xf bank_mask:0xf"
#define ROTMOD_7  "row_ror:7 row_mask:0xf bank_mask:0xf"
#define ROTMOD_8  "row_ror:8 row_mask:0xf bank_mask:0xf"
#define ROTMOD_9  "row_ror:9 row_mask:0xf bank_mask:0xf"
#define ROTMOD_10 "row_ror:10 row_mask:0xf bank_mask:0xf"
#define ROTMOD_11 "row_ror:11 row_mask:0xf bank_mask:0xf"
#define ROTMOD_12 "row_ror:12 row_mask:0xf bank_mask:0xf"
#define ROTMOD_13 "row_ror:13 row_mask:0xf bank_mask:0xf"
#define ROTMOD_14 "row_ror:14 row_mask:0xf bank_mask:0xf"
#define ROTMOD_15 "row_ror:15 row_mask:0xf bank_mask:0xf"

__global__ __launch_bounds__(128, 1) void k4_crf(
    const int* __restrict__ words, const int* __restrict__ tags,
    const float* __restrict__ emis, const float* __restrict__ trans,
    const float* __restrict__ st, const float* __restrict__ et,
    float* __restrict__ out) {
  const int b = blockIdx.x;
  const int tid = threadIdx.x;
  const int j = tid & 63;
  __shared__ float res[2];

  if (tid >= 64) {
    // ---- wave 1: numerator (gold path score) ----
    float s = 0.f;
    int cnt = 0;
#pragma unroll 1
    for (int s8 = 0; s8 < 8; ++s8) {
      const int t = j + (s8 << 6);
      const int wv = words[b * 512 + t];
      const int tg = tags[b * 512 + t];
      const bool mt = (wv != 0);
      cnt += mt ? 1 : 0;
      if (t == 0) {
        s += st[tg] + emis[b * 48 + tg];
      } else if (mt) {
        const int tp = tags[b * 512 + t - 1];
        s += trans[tp * 48 + tg] + emis[(t * 256 + b) * 48 + tg];
      }
    }
#pragma unroll
    for (int d = 32; d; d >>= 1) {
      s += __shfl_xor(s, d, 64);
      cnt += __shfl_xor(cnt, d, 64);
    }
    if (j == 0) {
      const int lt = tags[b * 512 + cnt - 1];
      res[1] = s + et[lt];
    }
  } else {
    // ---- wave 0: denominator, forward algorithm in linear domain ----
    const bool v = j < 48;

    // self-calibration: discover source index of each (m,k) gather slot
    float pcr[64];
    {
      float pm[4];
      const float pj = (float)j;
      pm[0] = pj;
      pm[1] = __shfl_xor(pj, 16, 64);
      pm[2] = __shfl_xor(pj, 32, 64);
      pm[3] = __shfl_xor(pj, 48, 64);
#define K4_CAL(m, k) { const int idx_ = (int)rotk<k>(pm[m]); \
      pcr[(m) * 16 + (k)] = (v && idx_ < 48) ? fexp2(trans[idx_ * 48 + j] * L2E) : 0.f; }
      K4_ALL(K4_CAL)
#undef K4_CAL
    }

    // mask bits: mb[q] bit s = (words[b*512 + q*64 + s] != 0)
    unsigned long long mb[8];
#pragma unroll
    for (int q = 0; q < 8; ++q)
      mb[q] = __ballot(words[b * 512 + q * 64 + j] != 0);

    float d = v ? fexp2((st[j] + emis[b * 48 + j]) * L2E) : 0.f;
    int S = 0, e_pend = 0;

    float em0 = v ? emis[(1 * 256 + b) * 48 + j] : 0.f;
    float em1 = v ? emis[(2 * 256 + b) * 48 + j] : 0.f;
    float em2 = v ? emis[(3 * 256 + b) * 48 + j] : 0.f;
    float em3 = v ? emis[(4 * 256 + b) * 48 + j] : 0.f;
    float Ecur = fexp2(em0 * L2E);

#pragma unroll 1
    for (int q = 0; q < 8; ++q) {
      const unsigned long long m = mb[q];
      const int s0 = (q == 0) ? 1 : 0;
#pragma unroll 1
      for (int s = s0; s < 64; ++s) {
        const int t = q * 64 + s;
        float E = Ecur;
        int eApp = 0;
        if ((s & 7) == 2) {   // fold lagged renorm into E (uniform branch)
          const float sc = __builtin_bit_cast(float, (uint_t)(127 - e_pend) << 23);
          E *= sc;
          eApp = e_pend;
        }
        const int tn = min(511, t + 4);
        em0 = em1; em1 = em2; em2 = em3;
        em3 = v ? emis[(tn * 256 + b) * 48 + j] : 0.f;  // vmcnt path, depth-4
        const float En = fexp2(em0 * L2E);              // E for t+1, off-chain

        // register all-gather matvec: nxt_j = sum_i d_i * P[i][j]
        float dm[4];
        dm[0] = d;
        dm[1] = __shfl_xor(d, 16, 64);
        dm[2] = __shfl_xor(d, 32, 64);
        dm[3] = __shfl_xor(d, 48, 64);
        float acc[8] = {0.f, 0.f, 0.f, 0.f, 0.f, 0.f, 0.f, 0.f};
#define K4_FMA(m, k) asm volatile( \
        "v_fmac_f32 %0, %1, %2 " ROTMOD_##k \
        : "+v"(acc[((m) * 16 + (k)) & 7]) \
        : "v"(dm[m]), "v"(pcr[(m) * 16 + (k)]));
        K4_ALL(K4_FMA)
#undef K4_FMA
        const float nxt = (((acc[0] + acc[1]) + (acc[2] + acc[3])) +
                           ((acc[4] + acc[5]) + (acc[6] + acc[7]))) * E;
        if ((m >> s) & 1ull) {   // wave-uniform scalar branch, no memory
          d = v ? nxt : 0.f;
          S += eApp;
        }
        if ((s & 7) == 0) {      // lagged exponent measurement (any lane works)
          const int db = __builtin_amdgcn_readfirstlane(__builtin_bit_cast(int, d));
          e_pend = ((db >> 23) & 0xff) - 127;
        }
        Ecur = En;
      }
    }
    float uf = v ? d * fexp2(et[j] * L2E) : 0.f;
#pragma unroll
    for (int dd = 32; dd; dd >>= 1) uf += __shfl_xor(uf, dd, 64);
    if (j == 0) res[0] = ((float)S + flog2(uf)) * LN2;
  }
  __syncthreads();
  // loss = -mean(num - denom)  ->  accumulate (denom - num)/256
  if (tid == 0) atomicAdd(out, (res[0] - res[1]) * (1.0f / 256.0f));
}

// ---------------------------------------------------------------------------
extern "C" void kernel_launch(void* const* d_in, const int* in_sizes, int n_in,
                              void* d_out, int out_size, void* d_ws, size_t ws_size,
                              hipStream_t stream) {
  (void)in_sizes; (void)n_in; (void)out_size; (void)ws_size;
  const int*   words = (const int*)d_in[0];
  const int*   tags  = (const int*)d_in[1];
  // d_in[2] = mask (bool) -- unused; reconstructed as words != 0
  const float* emb   = (const float*)d_in[3];
  const float* Wih_f = (const float*)d_in[4];
  const float* Whh_f = (const float*)d_in[5];
  const float* bih_f = (const float*)d_in[6];
  const float* bhh_f = (const float*)d_in[7];
  const float* Wih_b = (const float*)d_in[8];
  const float* Whh_b = (const float*)d_in[9];
  const float* bih_b = (const float*)d_in[10];
  const float* bhh_b = (const float*)d_in[11];
  const float* Wout  = (const float*)d_in[12];
  const float* bout  = (const float*)d_in[13];
  const float* trans = (const float*)d_in[14];
  const float* st    = (const float*)d_in[15];
  const float* et    = (const float*)d_in[16];

  char* ws = (char*)d_ws;
  ushort_t* h_f   = (ushort_t*)(ws);                    // 33,554,432 B
  ushort_t* h_b   = (ushort_t*)(ws + 33554432);         // 33,554,432 B
  float*    emis  = (float*)   (ws + 67108864);         // 25,165,824 B
  // total ws needed: ~92.3 MB (within the known-good 125.8 MB envelope)

  k2_lstm <<<256, 512, 0, stream>>>(words, emb,
                                    Wih_f, Whh_f, bih_f, bhh_f,
                                    Wih_b, Whh_b, bih_b, bhh_b,
                                    h_f, h_b);
  k3_emis <<<1024, 256, 0, stream>>>(h_f, h_b, Wout, bout, emis, (float*)d_out);
  k4_crf  <<<256, 128, 0, stream>>>(words, tags, emis, trans, st, et, (float*)d_out);
}

// Round 7
// 558.093 us; speedup vs baseline: 1.4877x; 1.0345x over previous
//
#include <hip/hip_runtime.h>
#include <hip/hip_bf16.h>

// Sizes (fixed by the reference)
//  V=32000, T=48, E=128, HID=256, H=128, B=256, L=512, 4H=512
typedef unsigned short ushort_t;
typedef unsigned int uint_t;
typedef __bf16 bf16x8 __attribute__((ext_vector_type(8)));
typedef float f32x4 __attribute__((ext_vector_type(4)));
typedef float f32x16 __attribute__((ext_vector_type(16)));

#define L2E 1.44269504088896340736f
#define LN2 0.69314718055994530942f

// LDS-only barrier: does NOT drain vmcnt -> global loads/stores stay in flight.
#define WGBAR() __asm__ volatile("s_waitcnt lgkmcnt(0)\n\ts_barrier" ::: "memory")

static __device__ __forceinline__ float fexp2(float x) { return __builtin_amdgcn_exp2f(x); }
static __device__ __forceinline__ float flog2(float x) { return __builtin_amdgcn_logf(x); }
static __device__ __forceinline__ float frcp (float x) { return __builtin_amdgcn_rcpf(x); }

static __device__ __forceinline__ float sigm(float x) {
  return frcp(1.0f + fexp2(-L2E * x));
}
static __device__ __forceinline__ float tanha(float x) {
  return 1.0f - 2.0f * frcp(1.0f + fexp2(2.0f * L2E * x));
}

// Hardware bf16 pair-convert (RNE). result = bf16(lo) | bf16(hi)<<16.
static __device__ __forceinline__ uint_t cvtpk(float lo, float hi) {
  uint_t r;
  asm("v_cvt_pk_bf16_f32 %0, %1, %2" : "=v"(r) : "v"(lo), "v"(hi));
  return r;
}
static __device__ __forceinline__ bf16x8 pack8(float4 a, float4 b) {
  uint4 u = make_uint4(cvtpk(a.x, a.y), cvtpk(a.z, a.w),
                       cvtpk(b.x, b.y), cvtpk(b.z, b.w));
  return __builtin_bit_cast(bf16x8, u);
}
static __device__ __forceinline__ bf16x8 zero8() {
  uint4 z = make_uint4(0u, 0u, 0u, 0u);
  return __builtin_bit_cast(bf16x8, z);
}
static __device__ __forceinline__ uint2 pack4(float4 a) {
  return make_uint2(cvtpk(a.x, a.y), cvtpk(a.z, a.w));
}

// DPP row-rotate-right by K within 16-lane rows (K=0 -> identity).
template <int K>
static __device__ __forceinline__ float rotk(float x) {
  if constexpr (K == 0) {
    return x;
  } else {
    return __builtin_bit_cast(float, __builtin_amdgcn_update_dpp(
        0, __builtin_bit_cast(int, x), 0x120 + K, 0xf, 0xf, true));
  }
}

// ---------------------------------------------------------------------------
// K2 v9 (unchanged from round 6 -- measured-good 309 us).
// ---------------------------------------------------------------------------
__global__ __launch_bounds__(512, 2) void k2_lstm(
    const int* __restrict__ words, const float* __restrict__ emb,
    const float* __restrict__ Wih_f, const float* __restrict__ Whh_f,
    const float* __restrict__ bih_f, const float* __restrict__ bhh_f,
    const float* __restrict__ Wih_b, const float* __restrict__ Whh_b,
    const float* __restrict__ bih_b, const float* __restrict__ bhh_b,
    ushort_t* __restrict__ h_f, ushort_t* __restrict__ h_b) {
  const int wg = blockIdx.x;
  const int dir = wg >> 7;
  const int r0 = (wg & 127) << 1;
  const float* Whh = dir ? Whh_b : Whh_f;
  const float* Wih = dir ? Wih_b : Wih_f;
  const float* bih = dir ? bih_b : bih_f;
  const float* bhh = dir ? bhh_b : bhh_f;
  ushort_t* hout = dir ? h_b : h_f;

  const int tid = threadIdx.x;
  const int w = tid >> 6;        // wave 0..7
  const int lane = tid & 63;
  const int l15 = lane & 15;
  const int kq = lane >> 4;      // 0..3

  __shared__ __align__(16) ushort_t hx[2][2][136];      //  1,088 B
  __shared__ __align__(16) ushort_t xp[2][16][128][4];  // 32,768 B
  __shared__ __align__(16) ushort_t xs[2][16][136];     //  8,704 B

  // ---- register-resident weight fragments (bf16), [quadrant][K-chunk] ----
  // B layout (16x16x32): col n = lane&15, k = (lane>>4)*8 + j
  bf16x8 wfh[4][4], wfx[4][4];
  float biasP[4];   // production bias for col w*16+l15, quadrant Q
#pragma unroll
  for (int Q = 0; Q < 4; ++Q) {
    const int n = Q * 128 + w * 16 + l15;
    biasP[Q] = bih[n] + bhh[n];
#pragma unroll
    for (int c = 0; c < 4; ++c) {
      const int k0 = c * 32 + kq * 8;
      const float* sh = Whh + n * 128 + k0;
      const float* sx = Wih + n * 128 + k0;
      wfh[Q][c] = pack8(*(const float4*)sh, *(const float4*)(sh + 4));
      wfx[Q][c] = pack8(*(const float4*)sx, *(const float4*)(sx + 4));
    }
  }

  const int ur = (lane >> 4) & 1;
  const int uj = w * 16 + l15;
  float cst = 0.f;
  const f32x4 fz = {0.f, 0.f, 0.f, 0.f};   // persistent MFMA C-init

  // staging thread mapping: 512 thr cover 16 rows x 128 cols (4 floats each)
  const int sm = tid >> 5;          // xs row 0..15  (tl = sm>>1, r = sm&1)
  const int sc = (tid & 31) * 4;    // col 0..124
  const int str = r0 + (sm & 1);
  const int stl = sm >> 1;

  // production pack registers (live across the 4 Q sub-phases of a block)
  uint_t pd0[4], pd1[4];
  f32x4 pc = {0.f, 0.f, 0.f, 0.f};
  f32x4 pcsv = {0.f, 0.f, 0.f, 0.f};

  // ---- prologue ----
  if (tid < 256) hx[0][tid >> 7][tid & 127] = 0;   // h(-1) = 0
  {  // stage xs[1] = x(block 0)
    const int tg = stl;
    const int tf = dir ? (511 - tg) : tg;
    const int word = words[str * 512 + tf];
    float4 av = *(const float4*)(emb + (size_t)word * 128 + sc);
    *(uint2*)&xs[1][sm][sc] = pack4(av);
  }
  WGBAR();
  // produce xp[0] from xs[1] (16 dense MFMAs/wave), bias in C-init
  {
    f32x4 qv[4];
#pragma unroll
    for (int Q = 0; Q < 4; ++Q) {
      f32x4 pc0 = {biasP[Q], biasP[Q], biasP[Q], biasP[Q]};
#pragma unroll
      for (int c = 0; c < 4; ++c) {
        bf16x8 af = __builtin_bit_cast(bf16x8, *(const uint4*)&xs[1][l15][kq * 8 + c * 32]);
        pc0 = __builtin_amdgcn_mfma_f32_16x16x32_bf16(af, wfx[Q][c], pc0, 0, 0, 0);
      }
      qv[Q] = pc0;
    }
#pragma unroll
    for (int rr = 0; rr < 4; ++rr) {
      pd0[rr] = cvtpk(qv[0][rr], qv[1][rr]);
      pd1[rr] = cvtpk(qv[2][rr], qv[3][rr]);
      *(uint2*)&xp[0][kq * 4 + rr][uj][0] = make_uint2(pd0[rr], pd1[rr]);
    }
  }
  {  // stage xs[0] = x(block 1)
    const int tg = 8 + stl;
    const int tf = dir ? (511 - tg) : tg;
    const int word = words[str * 512 + tf];
    float4 av = *(const float4*)(emb + (size_t)word * 128 + sc);
    *(uint2*)&xs[0][sm][sc] = pack4(av);
  }
  WGBAR();

  int sword = 0;
  float4 se0 = make_float4(0.f, 0.f, 0.f, 0.f);

#pragma unroll 1
  for (int i = 0; i < 64; ++i) {   // 64 blocks of 8 steps
    const int pcon = i & 1;        // consume xp[pcon]; production reads xs[pcon]
    const int ppro = pcon ^ 1;     // produce xp[ppro]; staging writes xs[ppro]
    // ---- per-block hoist: production A-fragments (xs[pcon] stable all block)
    bf16x8 afp[4];
    if (i < 63) {
#pragma unroll
      for (int c = 0; c < 4; ++c)
        afp[c] = __builtin_bit_cast(bf16x8, *(const uint4*)&xs[pcon][l15][kq * 8 + c * 32]);
    }
#pragma unroll
    for (int s = 0; s < 8; ++s) {
      const int t = i * 8 + s;
      const int p = t & 1;
      // xp consumption: one b64 read (Q0..Q3 packed for this lane's (ur,uj))
      const uint2 xq = *(const uint2*)&xp[pcon][2 * s + ur][uj][0];
      // staging pipeline for x(block i+2): word @s0, emb @s2, LDS write @s6
      if (i < 62) {
        if (s == 0) {
          const int tg = (i + 2) * 8 + stl;
          const int tf = dir ? (511 - tg) : tg;
          sword = words[str * 512 + tf];
        }
        if (s == 2) se0 = *(const float4*)(emb + (size_t)sword * 128 + sc);
        if (s == 6) *(uint2*)&xs[ppro][sm][sc] = pack4(se0);
      }
      // ---- recurrence MFMAs: gates_h = h @ Whh^T (K=128); C-init = fz ----
      f32x4 a0, a1, a2, a3;
      const ushort_t* abase = &hx[p][l15 & 1][kq * 8];
      {
        bf16x8 af = __builtin_bit_cast(bf16x8, *(const uint4*)(abase));
        a0 = __builtin_amdgcn_mfma_f32_16x16x32_bf16(af, wfh[0][0], fz, 0, 0, 0);
        a1 = __builtin_amdgcn_mfma_f32_16x16x32_bf16(af, wfh[1][0], fz, 0, 0, 0);
        a2 = __builtin_amdgcn_mfma_f32_16x16x32_bf16(af, wfh[2][0], fz, 0, 0, 0);
        a3 = __builtin_amdgcn_mfma_f32_16x16x32_bf16(af, wfh[3][0], fz, 0, 0, 0);
      }
#pragma unroll
      for (int c = 1; c < 4; ++c) {
        bf16x8 af = __builtin_bit_cast(bf16x8, *(const uint4*)(abase + c * 32));
        a0 = __builtin_amdgcn_mfma_f32_16x16x32_bf16(af, wfh[0][c], a0, 0, 0, 0);
        a1 = __builtin_amdgcn_mfma_f32_16x16x32_bf16(af, wfh[1][c], a1, 0, 0, 0);
        a2 = __builtin_amdgcn_mfma_f32_16x16x32_bf16(af, wfh[2][c], a2, 0, 0, 0);
        a3 = __builtin_amdgcn_mfma_f32_16x16x32_bf16(af, wfh[3][c], a3, 0, 0, 0);
      }
      // ---- production MFMAs for block i+1 (independent; fills bubbles) ----
      if (i < 63) {
        const int Q = s >> 1;
        if ((s & 1) == 0) {
          pc = f32x4{biasP[Q], biasP[Q], biasP[Q], biasP[Q]};
          pc = __builtin_amdgcn_mfma_f32_16x16x32_bf16(afp[0], wfx[Q][0], pc, 0, 0, 0);
          pc = __builtin_amdgcn_mfma_f32_16x16x32_bf16(afp[1], wfx[Q][1], pc, 0, 0, 0);
        } else {
          pc = __builtin_amdgcn_mfma_f32_16x16x32_bf16(afp[2], wfx[Q][2], pc, 0, 0, 0);
          pc = __builtin_amdgcn_mfma_f32_16x16x32_bf16(afp[3], wfx[Q][3], pc, 0, 0, 0);
          if ((s & 2) == 0) {          // s==1 (Q0) or s==5 (Q2): save
            pcsv = pc;
          } else if (s == 3) {         // Q1 done: pd0 = pack(Q0, Q1)
#pragma unroll
            for (int rr = 0; rr < 4; ++rr) pd0[rr] = cvtpk(pcsv[rr], pc[rr]);
          } else {                     // s==7, Q3: pd1 = pack(Q2, Q3) + write
#pragma unroll
            for (int rr = 0; rr < 4; ++rr) {
              pd1[rr] = cvtpk(pcsv[rr], pc[rr]);
              *(uint2*)&xp[ppro][kq * 4 + rr][uj][0] = make_uint2(pd0[rr], pd1[rr]);
            }
          }
        }
      }
      // ---- gates: lane's own (ur,uj) pair -- reg[0]=batch0, reg[1]=batch1
      const float g0 = (ur ? a0[1] : a0[0]) + __builtin_bit_cast(float, xq.x << 16);
      const float g1 = (ur ? a1[1] : a1[0]) + __builtin_bit_cast(float, xq.x & 0xffff0000u);
      const float g2 = (ur ? a2[1] : a2[0]) + __builtin_bit_cast(float, xq.y << 16);
      const float g3 = (ur ? a3[1] : a3[0]) + __builtin_bit_cast(float, xq.y & 0xffff0000u);
      // activations (one chain per lane; lanes>=32 duplicate, stores guarded)
      const float si = sigm(g0), sf = sigm(g1), so = sigm(g3);
      const float tg = tanha(g2);
      cst = sf * cst + si * tg;
      const float h = so * tanha(cst);
      const ushort_t hb = (ushort_t)cvtpk(h, h);
      if (lane < 32) {
        hx[p ^ 1][ur][uj] = hb;
        const int tf = dir ? (511 - t) : t;
        hout[(tf * 256 + r0 + ur) * 128 + uj] = hb;  // stays in flight
      }
      WGBAR();
    }
  }
}

// ---------------------------------------------------------------------------
// K3: emis[t*256+b][48] = [h_f|h_b] @ Wout^T + bout  (fp32 out)
// Also zeroes the loss accumulator (block 0, thread 0) so K4 can atomicAdd.
// ---------------------------------------------------------------------------
__global__ __launch_bounds__(256, 2) void k3_emis(
    const ushort_t* __restrict__ h_f, const ushort_t* __restrict__ h_b,
    const float* __restrict__ Wout, const float* __restrict__ bout,
    float* __restrict__ emis, float* __restrict__ loss_out) {
  if (blockIdx.x == 0 && threadIdx.x == 0) loss_out[0] = 0.f;
  const int w = threadIdx.x >> 6;
  const int lane = threadIdx.x & 63;
  const int m31 = lane & 31;
  const int q = lane >> 5;
  const int Mbase = blockIdx.x * 128 + w * 32;

  bf16x8 bfr[2][16];
  float bo[2];
#pragma unroll
  for (int T = 0; T < 2; ++T) {
    const int n = T * 32 + m31;
    if (n < 48) {
      bo[T] = bout[n];
#pragma unroll
      for (int c = 0; c < 16; ++c) {
        const float* src = Wout + n * 256 + c * 16 + q * 8;
        bfr[T][c] = pack8(*(const float4*)src, *(const float4*)(src + 4));
      }
    } else {
      bo[T] = 0.f;
#pragma unroll
      for (int c = 0; c < 16; ++c) bfr[T][c] = zero8();
    }
  }
  f32x16 acc0{}, acc1{};
  const ushort_t* hrf = h_f + (long)(Mbase + m31) * 128;
  const ushort_t* hrb = h_b + (long)(Mbase + m31) * 128;
#pragma unroll
  for (int c = 0; c < 16; ++c) {
    const ushort_t* src = (c < 8) ? (hrf + c * 16 + q * 8) : (hrb + (c - 8) * 16 + q * 8);
    bf16x8 af = __builtin_bit_cast(bf16x8, *(const uint4*)src);
    acc0 = __builtin_amdgcn_mfma_f32_32x32x16_bf16(af, bfr[0][c], acc0, 0, 0, 0);
    acc1 = __builtin_amdgcn_mfma_f32_32x32x16_bf16(af, bfr[1][c], acc1, 0, 0, 0);
  }
#pragma unroll
  for (int T = 0; T < 2; ++T) {
    const int n = T * 32 + m31;
    if (n >= 48) continue;
    f32x16 A = T ? acc1 : acc0;
#pragma unroll
    for (int r = 0; r < 16; ++r) {
      const int row = (r & 3) + ((r >> 2) << 3) + (q << 2);
      emis[(long)(Mbase + row) * 48 + n] = A[r] + bo[T];
    }
  }
}

// ---------------------------------------------------------------------------
// K4 v10: fused CRF. Round-6 diagnosis: the per-step `em3 = v ? load : 0`
// cndmask reads the load's dest register in the SAME iteration it is issued
// -> compiler inserts s_waitcnt vmcnt(0) at the cndmask -> every one of the
// 512 serial steps ate a full cold-read latency (~500cy; emis rows are
// block-private, L2-miss/L3-hit). The "depth-4 prefetch" never prefetched.
// Fix:
//  - loads use clamped index jj (in-bounds for all lanes, no select on the
//    load path; lanes>=48 read junk that pcr=0 / d-mask annihilate)
//  - inner loop 4-way unrolled (t=1..3 peeled) so em0..em3 rotation becomes
//    static renaming; the vmcnt wait lands at the use, ~3 steps after issue.
//  - fmac asm no longer volatile (scheduler may interleave).
// ---------------------------------------------------------------------------
#define K4_ROW(OP, m) \
  OP(m, 0) OP(m, 1) OP(m, 2) OP(m, 3) OP(m, 4) OP(m, 5) OP(m, 6) OP(m, 7) \
  OP(m, 8) OP(m, 9) OP(m, 10) OP(m, 11) OP(m, 12) OP(m, 13) OP(m, 14) OP(m, 15)
#define K4_ALL(OP) K4_ROW(OP, 0) K4_ROW(OP, 1) K4_ROW(OP, 2) K4_ROW(OP, 3)

#define ROTMOD_0  ""
#define ROTMOD_1  "row_ror:1 row_mask:0xf bank_mask:0xf"
#define ROTMOD_2  "row_ror:2 row_mask:0xf bank_mask:0xf"
#define ROTMOD_3  "row_ror:3 row_mask:0xf bank_mask:0xf"
#define ROTMOD_4  "row_ror:4 row_mask:0xf bank_mask:0xf"
#define ROTMOD_5  "row_ror:5 row_mask:0xf bank_mask:0xf"
#define ROTMOD_6  "row_ror:6 row_mask:0xf bank_mask:0xf"
#define ROTMOD_7  "row_ror:7 row_mask:0xf bank_mask:0xf"
#define ROTMOD_8  "row_ror:8 row_mask:0xf bank_mask:0xf"
#define ROTMOD_9  "row_ror:9 row_mask:0xf bank_mask:0xf"
#define ROTMOD_10 "row_ror:10 row_mask:0xf bank_mask:0xf"
#define ROTMOD_11 "row_ror:11 row_mask:0xf bank_mask:0xf"
#define ROTMOD_12 "row_ror:12 row_mask:0xf bank_mask:0xf"
#define ROTMOD_13 "row_ror:13 row_mask:0xf bank_mask:0xf"
#define ROTMOD_14 "row_ror:14 row_mask:0xf bank_mask:0xf"
#define ROTMOD_15 "row_ror:15 row_mask:0xf bank_mask:0xf"

__global__ __launch_bounds__(128, 1) void k4_crf(
    const int* __restrict__ words, const int* __restrict__ tags,
    const float* __restrict__ emis, const float* __restrict__ trans,
    const float* __restrict__ st, const float* __restrict__ et,
    float* __restrict__ out) {
  const int b = blockIdx.x;
  const int tid = threadIdx.x;
  const int j = tid & 63;
  __shared__ float res[2];

  if (tid >= 64) {
    // ---- wave 1: numerator (gold path score) ----
    float s = 0.f;
    int cnt = 0;
#pragma unroll 1
    for (int s8 = 0; s8 < 8; ++s8) {
      const int t = j + (s8 << 6);
      const int wv = words[b * 512 + t];
      const int tg = tags[b * 512 + t];
      const bool mt = (wv != 0);
      cnt += mt ? 1 : 0;
      if (t == 0) {
        s += st[tg] + emis[b * 48 + tg];
      } else if (mt) {
        const int tp = tags[b * 512 + t - 1];
        s += trans[tp * 48 + tg] + emis[(t * 256 + b) * 48 + tg];
      }
    }
#pragma unroll
    for (int d = 32; d; d >>= 1) {
      s += __shfl_xor(s, d, 64);
      cnt += __shfl_xor(cnt, d, 64);
    }
    if (j == 0) {
      const int lt = tags[b * 512 + cnt - 1];
      res[1] = s + et[lt];
    }
  } else {
    // ---- wave 0: denominator, forward algorithm in linear domain ----
    const bool v = j < 48;
    const int jj = v ? j : 47;   // clamped: all lanes load in-bounds

    // self-calibration: discover source index of each (m,k) gather slot
    float pcr[64];
    {
      float pm[4];
      const float pj = (float)j;
      pm[0] = pj;
      pm[1] = __shfl_xor(pj, 16, 64);
      pm[2] = __shfl_xor(pj, 32, 64);
      pm[3] = __shfl_xor(pj, 48, 64);
#define K4_CAL(m, k) { const int idx_ = (int)rotk<k>(pm[m]); \
      pcr[(m) * 16 + (k)] = (v && idx_ < 48) ? fexp2(trans[idx_ * 48 + j] * L2E) : 0.f; }
      K4_ALL(K4_CAL)
#undef K4_CAL
    }

    // mask bits: mb[q] bit s = (words[b*512 + q*64 + s] != 0)
    unsigned long long mb[8];
#pragma unroll
    for (int q = 0; q < 8; ++q)
      mb[q] = __ballot(words[b * 512 + q * 64 + j] != 0);

    float d = v ? fexp2((st[j] + emis[b * 48 + j]) * L2E) : 0.f;
    int S = 0, e_pend = 0;

    // emis prefetch pipeline, depth 4, UNCONDITIONAL clamped loads
    float em0 = emis[(1 * 256 + b) * 48 + jj];
    float em1 = emis[(2 * 256 + b) * 48 + jj];
    float em2 = emis[(3 * 256 + b) * 48 + jj];
    float em3 = emis[(4 * 256 + b) * 48 + jj];
    float Ecur = fexp2(em0 * L2E);

    // one CRF forward step; caller guarantees static s (peeled/unrolled)
    auto STEP = [&](int t, unsigned long long m, int s) {
      float E = Ecur;
      int eApp = 0;
      if ((s & 7) == 2) {   // fold lagged renorm into E (uniform branch)
        const float sc = __builtin_bit_cast(float, (uint_t)(127 - e_pend) << 23);
        E *= sc;
        eApp = e_pend;
      }
      const int tn = min(511, t + 4);
      em0 = em1; em1 = em2; em2 = em3;            // static renaming after unroll
      em3 = emis[(tn * 256 + b) * 48 + jj];       // no select: wait lands at use
      const float En = fexp2(em0 * L2E);          // E for t+1, off-chain

      // register all-gather matvec: nxt_j = sum_i d_i * P[i][j]
      float dm[4];
      dm[0] = d;
      dm[1] = __shfl_xor(d, 16, 64);
      dm[2] = __shfl_xor(d, 32, 64);
      dm[3] = __shfl_xor(d, 48, 64);
      float acc[8] = {0.f, 0.f, 0.f, 0.f, 0.f, 0.f, 0.f, 0.f};
#define K4_FMA(m_, k_) asm( \
      "v_fmac_f32 %0, %1, %2 " ROTMOD_##k_ \
      : "+v"(acc[((m_) * 16 + (k_)) & 7]) \
      : "v"(dm[m_]), "v"(pcr[(m_) * 16 + (k_)]));
      K4_ALL(K4_FMA)
#undef K4_FMA
      const float nxt = (((acc[0] + acc[1]) + (acc[2] + acc[3])) +
                         ((acc[4] + acc[5]) + (acc[6] + acc[7]))) * E;
      if ((m >> s) & 1ull) {   // wave-uniform scalar branch, no memory
        d = v ? nxt : 0.f;
        S += eApp;
      }
      if ((s & 7) == 0) {      // lagged exponent measurement (any lane works)
        const int db = __builtin_amdgcn_readfirstlane(__builtin_bit_cast(int, d));
        e_pend = ((db >> 23) & 0xff) - 127;
      }
      Ecur = En;
    };

    {  // q = 0: peel s = 1..3, then 60 steps unrolled by 4
      const unsigned long long m = mb[0];
      STEP(1, m, 1); STEP(2, m, 2); STEP(3, m, 3);
#pragma unroll 4
      for (int s = 4; s < 64; ++s) STEP(s, m, s);
    }
#pragma unroll 1
    for (int q = 1; q < 8; ++q) {
      const unsigned long long m = mb[q];
#pragma unroll 4
      for (int s = 0; s < 64; ++s) STEP(q * 64 + s, m, s);
    }

    float uf = v ? d * fexp2(et[j] * L2E) : 0.f;
#pragma unroll
    for (int dd = 32; dd; dd >>= 1) uf += __shfl_xor(uf, dd, 64);
    if (j == 0) res[0] = ((float)S + flog2(uf)) * LN2;
  }
  __syncthreads();
  // loss = -mean(num - denom)  ->  accumulate (denom - num)/256
  if (tid == 0) atomicAdd(out, (res[0] - res[1]) * (1.0f / 256.0f));
}

// ---------------------------------------------------------------------------
extern "C" void kernel_launch(void* const* d_in, const int* in_sizes, int n_in,
                              void* d_out, int out_size, void* d_ws, size_t ws_size,
                              hipStream_t stream) {
  (void)in_sizes; (void)n_in; (void)out_size; (void)ws_size;
  const int*   words = (const int*)d_in[0];
  const int*   tags  = (const int*)d_in[1];
  // d_in[2] = mask (bool) -- unused; reconstructed as words != 0
  const float* emb   = (const float*)d_in[3];
  const float* Wih_f = (const float*)d_in[4];
  const float* Whh_f = (const float*)d_in[5];
  const float* bih_f = (const float*)d_in[6];
  const float* bhh_f = (const float*)d_in[7];
  const float* Wih_b = (const float*)d_in[8];
  const float* Whh_b = (const float*)d_in[9];
  const float* bih_b = (const float*)d_in[10];
  const float* bhh_b = (const float*)d_in[11];
  const float* Wout  = (const float*)d_in[12];
  const float* bout  = (const float*)d_in[13];
  const float* trans = (const float*)d_in[14];
  const float* st    = (const float*)d_in[15];
  const float* et    = (const float*)d_in[16];

  char* ws = (char*)d_ws;
  ushort_t* h_f   = (ushort_t*)(ws);                    // 33,554,432 B
  ushort_t* h_b   = (ushort_t*)(ws + 33554432);         // 33,554,432 B
  float*    emis  = (float*)   (ws + 67108864);         // 25,165,824 B
  // total ws needed: ~92.3 MB (within the known-good 125.8 MB envelope)

  k2_lstm <<<256, 512, 0, stream>>>(words, emb,
                                    Wih_f, Whh_f, bih_f, bhh_f,
                                    Wih_b, Whh_b, bih_b, bhh_b,
                                    h_f, h_b);
  k3_emis <<<1024, 256, 0, stream>>>(h_f, h_b, Wout, bout, emis, (float*)d_out);
  k4_crf  <<<256, 128, 0, stream>>>(words, tags, emis, trans, st, et, (float*)d_out);
}

// Round 8
// 550.173 us; speedup vs baseline: 1.5092x; 1.0144x over previous
//
#include <hip/hip_runtime.h>
#include <hip/hip_bf16.h>

// Sizes (fixed by the reference)
//  V=32000, T=48, E=128, HID=256, H=128, B=256, L=512, 4H=512
typedef unsigned short ushort_t;
typedef unsigned int uint_t;
typedef __bf16 bf16x8 __attribute__((ext_vector_type(8)));
typedef float f32x4 __attribute__((ext_vector_type(4)));
typedef float f32x16 __attribute__((ext_vector_type(16)));

#define L2E 1.44269504088896340736f
#define LN2 0.69314718055994530942f

// LDS-only barrier: does NOT drain vmcnt -> global loads/stores stay in flight.
#define WGBAR() __asm__ volatile("s_waitcnt lgkmcnt(0)\n\ts_barrier" ::: "memory")

static __device__ __forceinline__ float fexp2(float x) { return __builtin_amdgcn_exp2f(x); }
static __device__ __forceinline__ float flog2(float x) { return __builtin_amdgcn_logf(x); }
static __device__ __forceinline__ float frcp (float x) { return __builtin_amdgcn_rcpf(x); }

static __device__ __forceinline__ float sigm(float x) {
  return frcp(1.0f + fexp2(-L2E * x));
}
static __device__ __forceinline__ float tanha(float x) {
  return 1.0f - 2.0f * frcp(1.0f + fexp2(2.0f * L2E * x));
}

// Hardware bf16 pair-convert (RNE). result = bf16(lo) | bf16(hi)<<16.
static __device__ __forceinline__ uint_t cvtpk(float lo, float hi) {
  uint_t r;
  asm("v_cvt_pk_bf16_f32 %0, %1, %2" : "=v"(r) : "v"(lo), "v"(hi));
  return r;
}
static __device__ __forceinline__ bf16x8 pack8(float4 a, float4 b) {
  uint4 u = make_uint4(cvtpk(a.x, a.y), cvtpk(a.z, a.w),
                       cvtpk(b.x, b.y), cvtpk(b.z, b.w));
  return __builtin_bit_cast(bf16x8, u);
}
static __device__ __forceinline__ bf16x8 zero8() {
  uint4 z = make_uint4(0u, 0u, 0u, 0u);
  return __builtin_bit_cast(bf16x8, z);
}
static __device__ __forceinline__ uint2 pack4(float4 a) {
  return make_uint2(cvtpk(a.x, a.y), cvtpk(a.z, a.w));
}

// DPP row-rotate-right by K within 16-lane rows (K=0 -> identity).
template <int K>
static __device__ __forceinline__ float rotk(float x) {
  if constexpr (K == 0) {
    return x;
  } else {
    return __builtin_bit_cast(float, __builtin_amdgcn_update_dpp(
        0, __builtin_bit_cast(int, x), 0x120 + K, 0xf, 0xf, true));
  }
}

// ---------------------------------------------------------------------------
// K2 v9 (unchanged from round 6 -- measured-good 309 us).
// ---------------------------------------------------------------------------
__global__ __launch_bounds__(512, 2) void k2_lstm(
    const int* __restrict__ words, const float* __restrict__ emb,
    const float* __restrict__ Wih_f, const float* __restrict__ Whh_f,
    const float* __restrict__ bih_f, const float* __restrict__ bhh_f,
    const float* __restrict__ Wih_b, const float* __restrict__ Whh_b,
    const float* __restrict__ bih_b, const float* __restrict__ bhh_b,
    ushort_t* __restrict__ h_f, ushort_t* __restrict__ h_b) {
  const int wg = blockIdx.x;
  const int dir = wg >> 7;
  const int r0 = (wg & 127) << 1;
  const float* Whh = dir ? Whh_b : Whh_f;
  const float* Wih = dir ? Wih_b : Wih_f;
  const float* bih = dir ? bih_b : bih_f;
  const float* bhh = dir ? bhh_b : bhh_f;
  ushort_t* hout = dir ? h_b : h_f;

  const int tid = threadIdx.x;
  const int w = tid >> 6;        // wave 0..7
  const int lane = tid & 63;
  const int l15 = lane & 15;
  const int kq = lane >> 4;      // 0..3

  __shared__ __align__(16) ushort_t hx[2][2][136];      //  1,088 B
  __shared__ __align__(16) ushort_t xp[2][16][128][4];  // 32,768 B
  __shared__ __align__(16) ushort_t xs[2][16][136];     //  8,704 B

  // ---- register-resident weight fragments (bf16), [quadrant][K-chunk] ----
  // B layout (16x16x32): col n = lane&15, k = (lane>>4)*8 + j
  bf16x8 wfh[4][4], wfx[4][4];
  float biasP[4];   // production bias for col w*16+l15, quadrant Q
#pragma unroll
  for (int Q = 0; Q < 4; ++Q) {
    const int n = Q * 128 + w * 16 + l15;
    biasP[Q] = bih[n] + bhh[n];
#pragma unroll
    for (int c = 0; c < 4; ++c) {
      const int k0 = c * 32 + kq * 8;
      const float* sh = Whh + n * 128 + k0;
      const float* sx = Wih + n * 128 + k0;
      wfh[Q][c] = pack8(*(const float4*)sh, *(const float4*)(sh + 4));
      wfx[Q][c] = pack8(*(const float4*)sx, *(const float4*)(sx + 4));
    }
  }

  const int ur = (lane >> 4) & 1;
  const int uj = w * 16 + l15;
  float cst = 0.f;
  const f32x4 fz = {0.f, 0.f, 0.f, 0.f};   // persistent MFMA C-init

  // staging thread mapping: 512 thr cover 16 rows x 128 cols (4 floats each)
  const int sm = tid >> 5;          // xs row 0..15  (tl = sm>>1, r = sm&1)
  const int sc = (tid & 31) * 4;    // col 0..124
  const int str = r0 + (sm & 1);
  const int stl = sm >> 1;

  // production pack registers (live across the 4 Q sub-phases of a block)
  uint_t pd0[4], pd1[4];
  f32x4 pc = {0.f, 0.f, 0.f, 0.f};
  f32x4 pcsv = {0.f, 0.f, 0.f, 0.f};

  // ---- prologue ----
  if (tid < 256) hx[0][tid >> 7][tid & 127] = 0;   // h(-1) = 0
  {  // stage xs[1] = x(block 0)
    const int tg = stl;
    const int tf = dir ? (511 - tg) : tg;
    const int word = words[str * 512 + tf];
    float4 av = *(const float4*)(emb + (size_t)word * 128 + sc);
    *(uint2*)&xs[1][sm][sc] = pack4(av);
  }
  WGBAR();
  // produce xp[0] from xs[1] (16 dense MFMAs/wave), bias in C-init
  {
    f32x4 qv[4];
#pragma unroll
    for (int Q = 0; Q < 4; ++Q) {
      f32x4 pc0 = {biasP[Q], biasP[Q], biasP[Q], biasP[Q]};
#pragma unroll
      for (int c = 0; c < 4; ++c) {
        bf16x8 af = __builtin_bit_cast(bf16x8, *(const uint4*)&xs[1][l15][kq * 8 + c * 32]);
        pc0 = __builtin_amdgcn_mfma_f32_16x16x32_bf16(af, wfx[Q][c], pc0, 0, 0, 0);
      }
      qv[Q] = pc0;
    }
#pragma unroll
    for (int rr = 0; rr < 4; ++rr) {
      pd0[rr] = cvtpk(qv[0][rr], qv[1][rr]);
      pd1[rr] = cvtpk(qv[2][rr], qv[3][rr]);
      *(uint2*)&xp[0][kq * 4 + rr][uj][0] = make_uint2(pd0[rr], pd1[rr]);
    }
  }
  {  // stage xs[0] = x(block 1)
    const int tg = 8 + stl;
    const int tf = dir ? (511 - tg) : tg;
    const int word = words[str * 512 + tf];
    float4 av = *(const float4*)(emb + (size_t)word * 128 + sc);
    *(uint2*)&xs[0][sm][sc] = pack4(av);
  }
  WGBAR();

  int sword = 0;
  float4 se0 = make_float4(0.f, 0.f, 0.f, 0.f);

#pragma unroll 1
  for (int i = 0; i < 64; ++i) {   // 64 blocks of 8 steps
    const int pcon = i & 1;        // consume xp[pcon]; production reads xs[pcon]
    const int ppro = pcon ^ 1;     // produce xp[ppro]; staging writes xs[ppro]
    // ---- per-block hoist: production A-fragments (xs[pcon] stable all block)
    bf16x8 afp[4];
    if (i < 63) {
#pragma unroll
      for (int c = 0; c < 4; ++c)
        afp[c] = __builtin_bit_cast(bf16x8, *(const uint4*)&xs[pcon][l15][kq * 8 + c * 32]);
    }
#pragma unroll
    for (int s = 0; s < 8; ++s) {
      const int t = i * 8 + s;
      const int p = t & 1;
      // xp consumption: one b64 read (Q0..Q3 packed for this lane's (ur,uj))
      const uint2 xq = *(const uint2*)&xp[pcon][2 * s + ur][uj][0];
      // staging pipeline for x(block i+2): word @s0, emb @s2, LDS write @s6
      if (i < 62) {
        if (s == 0) {
          const int tg = (i + 2) * 8 + stl;
          const int tf = dir ? (511 - tg) : tg;
          sword = words[str * 512 + tf];
        }
        if (s == 2) se0 = *(const float4*)(emb + (size_t)sword * 128 + sc);
        if (s == 6) *(uint2*)&xs[ppro][sm][sc] = pack4(se0);
      }
      // ---- recurrence MFMAs: gates_h = h @ Whh^T (K=128); C-init = fz ----
      f32x4 a0, a1, a2, a3;
      const ushort_t* abase = &hx[p][l15 & 1][kq * 8];
      {
        bf16x8 af = __builtin_bit_cast(bf16x8, *(const uint4*)(abase));
        a0 = __builtin_amdgcn_mfma_f32_16x16x32_bf16(af, wfh[0][0], fz, 0, 0, 0);
        a1 = __builtin_amdgcn_mfma_f32_16x16x32_bf16(af, wfh[1][0], fz, 0, 0, 0);
        a2 = __builtin_amdgcn_mfma_f32_16x16x32_bf16(af, wfh[2][0], fz, 0, 0, 0);
        a3 = __builtin_amdgcn_mfma_f32_16x16x32_bf16(af, wfh[3][0], fz, 0, 0, 0);
      }
#pragma unroll
      for (int c = 1; c < 4; ++c) {
        bf16x8 af = __builtin_bit_cast(bf16x8, *(const uint4*)(abase + c * 32));
        a0 = __builtin_amdgcn_mfma_f32_16x16x32_bf16(af, wfh[0][c], a0, 0, 0, 0);
        a1 = __builtin_amdgcn_mfma_f32_16x16x32_bf16(af, wfh[1][c], a1, 0, 0, 0);
        a2 = __builtin_amdgcn_mfma_f32_16x16x32_bf16(af, wfh[2][c], a2, 0, 0, 0);
        a3 = __builtin_amdgcn_mfma_f32_16x16x32_bf16(af, wfh[3][c], a3, 0, 0, 0);
      }
      // ---- production MFMAs for block i+1 (independent; fills bubbles) ----
      if (i < 63) {
        const int Q = s >> 1;
        if ((s & 1) == 0) {
          pc = f32x4{biasP[Q], biasP[Q], biasP[Q], biasP[Q]};
          pc = __builtin_amdgcn_mfma_f32_16x16x32_bf16(afp[0], wfx[Q][0], pc, 0, 0, 0);
          pc = __builtin_amdgcn_mfma_f32_16x16x32_bf16(afp[1], wfx[Q][1], pc, 0, 0, 0);
        } else {
          pc = __builtin_amdgcn_mfma_f32_16x16x32_bf16(afp[2], wfx[Q][2], pc, 0, 0, 0);
          pc = __builtin_amdgcn_mfma_f32_16x16x32_bf16(afp[3], wfx[Q][3], pc, 0, 0, 0);
          if ((s & 2) == 0) {          // s==1 (Q0) or s==5 (Q2): save
            pcsv = pc;
          } else if (s == 3) {         // Q1 done: pd0 = pack(Q0, Q1)
#pragma unroll
            for (int rr = 0; rr < 4; ++rr) pd0[rr] = cvtpk(pcsv[rr], pc[rr]);
          } else {                     // s==7, Q3: pd1 = pack(Q2, Q3) + write
#pragma unroll
            for (int rr = 0; rr < 4; ++rr) {
              pd1[rr] = cvtpk(pcsv[rr], pc[rr]);
              *(uint2*)&xp[ppro][kq * 4 + rr][uj][0] = make_uint2(pd0[rr], pd1[rr]);
            }
          }
        }
      }
      // ---- gates: lane's own (ur,uj) pair -- reg[0]=batch0, reg[1]=batch1
      const float g0 = (ur ? a0[1] : a0[0]) + __builtin_bit_cast(float, xq.x << 16);
      const float g1 = (ur ? a1[1] : a1[0]) + __builtin_bit_cast(float, xq.x & 0xffff0000u);
      const float g2 = (ur ? a2[1] : a2[0]) + __builtin_bit_cast(float, xq.y << 16);
      const float g3 = (ur ? a3[1] : a3[0]) + __builtin_bit_cast(float, xq.y & 0xffff0000u);
      // activations (one chain per lane; lanes>=32 duplicate, stores guarded)
      const float si = sigm(g0), sf = sigm(g1), so = sigm(g3);
      const float tg = tanha(g2);
      cst = sf * cst + si * tg;
      const float h = so * tanha(cst);
      const ushort_t hb = (ushort_t)cvtpk(h, h);
      if (lane < 32) {
        hx[p ^ 1][ur][uj] = hb;
        const int tf = dir ? (511 - t) : t;
        hout[(tf * 256 + r0 + ur) * 128 + uj] = hb;  // stays in flight
      }
      WGBAR();
    }
  }
}

// ---------------------------------------------------------------------------
// K3: emis[t*256+b][48] = [h_f|h_b] @ Wout^T + bout  (fp32 out)
// Also zeroes the loss accumulator (block 0, thread 0) so K4 can atomicAdd.
// ---------------------------------------------------------------------------
__global__ __launch_bounds__(256, 2) void k3_emis(
    const ushort_t* __restrict__ h_f, const ushort_t* __restrict__ h_b,
    const float* __restrict__ Wout, const float* __restrict__ bout,
    float* __restrict__ emis, float* __restrict__ loss_out) {
  if (blockIdx.x == 0 && threadIdx.x == 0) loss_out[0] = 0.f;
  const int w = threadIdx.x >> 6;
  const int lane = threadIdx.x & 63;
  const int m31 = lane & 31;
  const int q = lane >> 5;
  const int Mbase = blockIdx.x * 128 + w * 32;

  bf16x8 bfr[2][16];
  float bo[2];
#pragma unroll
  for (int T = 0; T < 2; ++T) {
    const int n = T * 32 + m31;
    if (n < 48) {
      bo[T] = bout[n];
#pragma unroll
      for (int c = 0; c < 16; ++c) {
        const float* src = Wout + n * 256 + c * 16 + q * 8;
        bfr[T][c] = pack8(*(const float4*)src, *(const float4*)(src + 4));
      }
    } else {
      bo[T] = 0.f;
#pragma unroll
      for (int c = 0; c < 16; ++c) bfr[T][c] = zero8();
    }
  }
  f32x16 acc0{}, acc1{};
  const ushort_t* hrf = h_f + (long)(Mbase + m31) * 128;
  const ushort_t* hrb = h_b + (long)(Mbase + m31) * 128;
#pragma unroll
  for (int c = 0; c < 16; ++c) {
    const ushort_t* src = (c < 8) ? (hrf + c * 16 + q * 8) : (hrb + (c - 8) * 16 + q * 8);
    bf16x8 af = __builtin_bit_cast(bf16x8, *(const uint4*)src);
    acc0 = __builtin_amdgcn_mfma_f32_32x32x16_bf16(af, bfr[0][c], acc0, 0, 0, 0);
    acc1 = __builtin_amdgcn_mfma_f32_32x32x16_bf16(af, bfr[1][c], acc1, 0, 0, 0);
  }
#pragma unroll
  for (int T = 0; T < 2; ++T) {
    const int n = T * 32 + m31;
    if (n >= 48) continue;
    f32x16 A = T ? acc1 : acc0;
#pragma unroll
    for (int r = 0; r < 16; ++r) {
      const int row = (r & 3) + ((r >> 2) << 3) + (q << 2);
      emis[(long)(Mbase + row) * 48 + n] = A[r] + bo[T];
    }
  }
}

// ---------------------------------------------------------------------------
// K4 v11: fused CRF. Round-7 insight: k4's ~900cy/step was INVARIANT across
// four matvec implementations -> the chain cost was never the matvec; it was
// the emis "prefetch" register rotation (em0=em1;...;em3=load). A v_mov from
// a register with a PENDING load forces s_waitcnt vmcnt(0) at the mov -- in
// the same step the load was issued. Every step ate full L3 latency.
// v11: depth-8 pipeline with explicitly NAMED registers em_0..em_7 and ZERO
// rotation movs. Rolled group loop (8 static step bodies, ~6KB code, fits
// L1I; full 511-step unroll would not). Step k of each group reloads em_k,
// consumed 7 steps later -> issue-to-use = 7 steps, latency covered. The
// t&7 renorm/measure cadence becomes compile-time static per body (peel
// t=1..7 aligns groups to t%8==0). Arithmetic order identical to the
// passing version.
// ---------------------------------------------------------------------------
#define K4_ROW(OP, m) \
  OP(m, 0) OP(m, 1) OP(m, 2) OP(m, 3) OP(m, 4) OP(m, 5) OP(m, 6) OP(m, 7) \
  OP(m, 8) OP(m, 9) OP(m, 10) OP(m, 11) OP(m, 12) OP(m, 13) OP(m, 14) OP(m, 15)
#define K4_ALL(OP) K4_ROW(OP, 0) K4_ROW(OP, 1) K4_ROW(OP, 2) K4_ROW(OP, 3)

#define ROTMOD_0  ""
#define ROTMOD_1  "row_ror:1 row_mask:0xf bank_mask:0xf"
#define ROTMOD_2  "row_ror:2 row_mask:0xf bank_mask:0xf"
#define ROTMOD_3  "row_ror:3 row_mask:0xf bank_mask:0xf"
#define ROTMOD_4  "row_ror:4 row_mask:0xf bank_mask:0xf"
#define ROTMOD_5  "row_ror:5 row_mask:0xf bank_mask:0xf"
#define ROTMOD_6  "row_ror:6 row_mask:0xf bank_mask:0xf"
#define ROTMOD_7  "row_ror:7 row_mask:0xf bank_mask:0xf"
#define ROTMOD_8  "row_ror:8 row_mask:0xf bank_mask:0xf"
#define ROTMOD_9  "row_ror:9 row_mask:0xf bank_mask:0xf"
#define ROTMOD_10 "row_ror:10 row_mask:0xf bank_mask:0xf"
#define ROTMOD_11 "row_ror:11 row_mask:0xf bank_mask:0xf"
#define ROTMOD_12 "row_ror:12 row_mask:0xf bank_mask:0xf"
#define ROTMOD_13 "row_ror:13 row_mask:0xf bank_mask:0xf"
#define ROTMOD_14 "row_ror:14 row_mask:0xf bank_mask:0xf"
#define ROTMOD_15 "row_ror:15 row_mask:0xf bank_mask:0xf"

#define K4_FMA(m_, k_) asm( \
    "v_fmac_f32 %0, %1, %2 " ROTMOD_##k_ \
    : "+v"(acc[((m_) * 16 + (k_)) & 7]) \
    : "v"(dm[m_]), "v"(pcr[(m_) * 16 + (k_)]));

// One CRF forward step. FOLD/MEAS are literal bools (fold at compile time);
// LOADSTMT reloads one named em register (issue-to-use distance = 7 steps);
// ENSRC is the named register holding emis[t+1].
#define K4_BODY(FOLD, LOADSTMT, ENSRC, MBIT, MEAS)                            \
  {                                                                           \
    float E = Ecur;                                                           \
    int eApp = 0;                                                             \
    if (FOLD) {                                                               \
      const float sc_ =                                                       \
          __builtin_bit_cast(float, (uint_t)(127 - e_pend) << 23);            \
      E *= sc_;                                                               \
      eApp = e_pend;                                                          \
    }                                                                         \
    LOADSTMT;                                                                 \
    const float En = fexp2((ENSRC) * L2E);                                    \
    float dm[4];                                                              \
    dm[0] = d;                                                                \
    dm[1] = __shfl_xor(d, 16, 64);                                            \
    dm[2] = __shfl_xor(d, 32, 64);                                            \
    dm[3] = __shfl_xor(d, 48, 64);                                            \
    float acc[8] = {0.f, 0.f, 0.f, 0.f, 0.f, 0.f, 0.f, 0.f};                  \
    K4_ALL(K4_FMA)                                                            \
    const float nxt = (((acc[0] + acc[1]) + (acc[2] + acc[3])) +              \
                       ((acc[4] + acc[5]) + (acc[6] + acc[7]))) * E;          \
    if (MBIT) {                                                               \
      d = v ? nxt : 0.f;                                                      \
      S += eApp;                                                              \
    }                                                                         \
    if (MEAS) {                                                               \
      const int db_ =                                                         \
          __builtin_amdgcn_readfirstlane(__builtin_bit_cast(int, d));         \
      e_pend = ((db_ >> 23) & 0xff) - 127;                                    \
    }                                                                         \
    Ecur = En;                                                                \
  }

__global__ __launch_bounds__(128, 1) void k4_crf(
    const int* __restrict__ words, const int* __restrict__ tags,
    const float* __restrict__ emis, const float* __restrict__ trans,
    const float* __restrict__ st, const float* __restrict__ et,
    float* __restrict__ out) {
  const int b = blockIdx.x;
  const int tid = threadIdx.x;
  const int j = tid & 63;
  __shared__ float res[2];

  if (tid >= 64) {
    // ---- wave 1: numerator (gold path score) ----
    float s = 0.f;
    int cnt = 0;
#pragma unroll 1
    for (int s8 = 0; s8 < 8; ++s8) {
      const int t = j + (s8 << 6);
      const int wv = words[b * 512 + t];
      const int tg = tags[b * 512 + t];
      const bool mt = (wv != 0);
      cnt += mt ? 1 : 0;
      if (t == 0) {
        s += st[tg] + emis[b * 48 + tg];
      } else if (mt) {
        const int tp = tags[b * 512 + t - 1];
        s += trans[tp * 48 + tg] + emis[(t * 256 + b) * 48 + tg];
      }
    }
#pragma unroll
    for (int d = 32; d; d >>= 1) {
      s += __shfl_xor(s, d, 64);
      cnt += __shfl_xor(cnt, d, 64);
    }
    if (j == 0) {
      const int lt = tags[b * 512 + cnt - 1];
      res[1] = s + et[lt];
    }
  } else {
    // ---- wave 0: denominator, forward algorithm in linear domain ----
    const bool v = j < 48;
    const int jj = v ? j : 47;   // clamped: all lanes load in-bounds

    // self-calibration: discover source index of each (m,k) gather slot
    float pcr[64];
    {
      float pm[4];
      const float pj = (float)j;
      pm[0] = pj;
      pm[1] = __shfl_xor(pj, 16, 64);
      pm[2] = __shfl_xor(pj, 32, 64);
      pm[3] = __shfl_xor(pj, 48, 64);
#define K4_CAL(m, k) { const int idx_ = (int)rotk<k>(pm[m]); \
      pcr[(m) * 16 + (k)] = (v && idx_ < 48) ? fexp2(trans[idx_ * 48 + j] * L2E) : 0.f; }
      K4_ALL(K4_CAL)
#undef K4_CAL
    }

    // mask bits: mb[q] bit s = (words[b*512 + q*64 + s] != 0); literal idx only
    unsigned long long mb[8];
#pragma unroll
    for (int q = 0; q < 8; ++q)
      mb[q] = __ballot(words[b * 512 + q * 64 + j] != 0);

    float d = v ? fexp2((st[j] + emis[b * 48 + j]) * L2E) : 0.f;
    int S = 0, e_pend = 0;

    const float* __restrict__ eb = emis + jj;
#define EMLD(tt) eb[(size_t)((tt) * 256 + b) * 48]

    // depth-8 pipeline prologue: 15 loads issued together
    float pm_0 = EMLD(1), pm_1 = EMLD(2), pm_2 = EMLD(3), pm_3 = EMLD(4);
    float pm_4 = EMLD(5), pm_5 = EMLD(6), pm_6 = EMLD(7);
    float em_0 = EMLD(8),  em_1 = EMLD(9),  em_2 = EMLD(10), em_3 = EMLD(11);
    float em_4 = EMLD(12), em_5 = EMLD(13), em_6 = EMLD(14), em_7 = EMLD(15);
    float Ecur = fexp2(pm_0 * L2E);   // E for t=1

    {  // peel t = 1..7 (q=0; aligns groups to t%8==0). t=2 is a fold step.
      const uint_t mm = (uint_t)mb[0];
      K4_BODY(false, (void)0, pm_1, (mm >> 1) & 1u, false)
      K4_BODY(true,  (void)0, pm_2, (mm >> 2) & 1u, false)
      K4_BODY(false, (void)0, pm_3, (mm >> 3) & 1u, false)
      K4_BODY(false, (void)0, pm_4, (mm >> 4) & 1u, false)
      K4_BODY(false, (void)0, pm_5, (mm >> 5) & 1u, false)
      K4_BODY(false, (void)0, pm_6, (mm >> 6) & 1u, false)
      K4_BODY(false, (void)0, em_0, (mm >> 7) & 1u, false)
    }

    // main: groups of 8 steps, t = G..G+7, G = 8..504 step 8. Step k
    // reloads em_k <- emis[G+8+k] (used 7 steps later); En source em_{k+1}
    // (em_0 at k=7 holds the value reloaded at k=0 = emis[G+8] -- exactly
    // the En needed). k==0: measure; k==2: fold. All static via macro.
#pragma unroll 1
    for (int q = 0; q < 8; ++q) {
      const unsigned long long mq =
          q == 0 ? mb[0] : q == 1 ? mb[1] : q == 2 ? mb[2] : q == 3 ? mb[3] :
          q == 4 ? mb[4] : q == 5 ? mb[5] : q == 6 ? mb[6] : mb[7];
#pragma unroll 1
      for (int gi = (q == 0 ? 1 : 0); gi < 8; ++gi) {
        const int G = q * 64 + gi * 8;
        const uint_t mm = (uint_t)(mq >> (gi * 8));
        const int Lb = G + 8;
        K4_BODY(false, em_0 = EMLD(min(511, Lb + 0)), em_1, (mm >> 0) & 1u, true)
        K4_BODY(false, em_1 = EMLD(min(511, Lb + 1)), em_2, (mm >> 1) & 1u, false)
        K4_BODY(true,  em_2 = EMLD(min(511, Lb + 2)), em_3, (mm >> 2) & 1u, false)
        K4_BODY(false, em_3 = EMLD(min(511, Lb + 3)), em_4, (mm >> 3) & 1u, false)
        K4_BODY(false, em_4 = EMLD(min(511, Lb + 4)), em_5, (mm >> 4) & 1u, false)
        K4_BODY(false, em_5 = EMLD(min(511, Lb + 5)), em_6, (mm >> 5) & 1u, false)
        K4_BODY(false, em_6 = EMLD(min(511, Lb + 6)), em_7, (mm >> 6) & 1u, false)
        K4_BODY(false, em_7 = EMLD(min(511, Lb + 7)), em_0, (mm >> 7) & 1u, false)
      }
    }
#undef EMLD

    float uf = v ? d * fexp2(et[j] * L2E) : 0.f;
#pragma unroll
    for (int dd = 32; dd; dd >>= 1) uf += __shfl_xor(uf, dd, 64);
    if (j == 0) res[0] = ((float)S + flog2(uf)) * LN2;
  }
  __syncthreads();
  // loss = -mean(num - denom)  ->  accumulate (denom - num)/256
  if (tid == 0) atomicAdd(out, (res[0] - res[1]) * (1.0f / 256.0f));
}

// ---------------------------------------------------------------------------
extern "C" void kernel_launch(void* const* d_in, const int* in_sizes, int n_in,
                              void* d_out, int out_size, void* d_ws, size_t ws_size,
                              hipStream_t stream) {
  (void)in_sizes; (void)n_in; (void)out_size; (void)ws_size;
  const int*   words = (const int*)d_in[0];
  const int*   tags  = (const int*)d_in[1];
  // d_in[2] = mask (bool) -- unused; reconstructed as words != 0
  const float* emb   = (const float*)d_in[3];
  const float* Wih_f = (const float*)d_in[4];
  const float* Whh_f = (const float*)d_in[5];
  const float* bih_f = (const float*)d_in[6];
  const float* bhh_f = (const float*)d_in[7];
  const float* Wih_b = (const float*)d_in[8];
  const float* Whh_b = (const float*)d_in[9];
  const float* bih_b = (const float*)d_in[10];
  const float* bhh_b = (const float*)d_in[11];
  const float* Wout  = (const float*)d_in[12];
  const float* bout  = (const float*)d_in[13];
  const float* trans = (const float*)d_in[14];
  const float* st    = (const float*)d_in[15];
  const float* et    = (const float*)d_in[16];

  char* ws = (char*)d_ws;
  ushort_t* h_f   = (ushort_t*)(ws);                    // 33,554,432 B
  ushort_t* h_b   = (ushort_t*)(ws + 33554432);         // 33,554,432 B
  float*    emis  = (float*)   (ws + 67108864);         // 25,165,824 B
  // total ws needed: ~92.3 MB (within the known-good 125.8 MB envelope)

  k2_lstm <<<256, 512, 0, stream>>>(words, emb,
                                    Wih_f, Whh_f, bih_f, bhh_f,
                                    Wih_b, Whh_b, bih_b, bhh_b,
                                    h_f, h_b);
  k3_emis <<<1024, 256, 0, stream>>>(h_f, h_b, Wout, bout, emis, (float*)d_out);
  k4_crf  <<<256, 128, 0, stream>>>(words, tags, emis, trans, st, et, (float*)d_out);
}

// Round 9
// 501.142 us; speedup vs baseline: 1.6568x; 1.0978x over previous
//
#include <hip/hip_runtime.h>
#include <hip/hip_bf16.h>

// Sizes (fixed by the reference)
//  V=32000, T=48, E=128, HID=256, H=128, B=256, L=512, 4H=512
typedef unsigned short ushort_t;
typedef unsigned int uint_t;
typedef __bf16 bf16x8 __attribute__((ext_vector_type(8)));
typedef float f32x4 __attribute__((ext_vector_type(4)));

#define L2E 1.44269504088896340736f
#define LN2 0.69314718055994530942f

// LDS-only barrier: does NOT drain vmcnt -> global loads/stores stay in flight.
#define WGBAR() __asm__ volatile("s_waitcnt lgkmcnt(0)\n\ts_barrier" ::: "memory")

static __device__ __forceinline__ float fexp2(float x) { return __builtin_amdgcn_exp2f(x); }
static __device__ __forceinline__ float flog2(float x) { return __builtin_amdgcn_logf(x); }
static __device__ __forceinline__ float frcp (float x) { return __builtin_amdgcn_rcpf(x); }

static __device__ __forceinline__ float sigm(float x) {
  return frcp(1.0f + fexp2(-L2E * x));
}
static __device__ __forceinline__ float tanha(float x) {
  return 1.0f - 2.0f * frcp(1.0f + fexp2(2.0f * L2E * x));
}

// Hardware bf16 pair-convert (RNE). result = bf16(lo) | bf16(hi)<<16.
static __device__ __forceinline__ uint_t cvtpk(float lo, float hi) {
  uint_t r;
  asm("v_cvt_pk_bf16_f32 %0, %1, %2" : "=v"(r) : "v"(lo), "v"(hi));
  return r;
}
static __device__ __forceinline__ bf16x8 pack8(float4 a, float4 b) {
  uint4 u = make_uint4(cvtpk(a.x, a.y), cvtpk(a.z, a.w),
                       cvtpk(b.x, b.y), cvtpk(b.z, b.w));
  return __builtin_bit_cast(bf16x8, u);
}
static __device__ __forceinline__ uint2 pack4(float4 a) {
  return make_uint2(cvtpk(a.x, a.y), cvtpk(a.z, a.w));
}

// DPP row-rotate-right by K within 16-lane rows (K=0 -> identity).
template <int K>
static __device__ __forceinline__ float rotk(float x) {
  if constexpr (K == 0) {
    return x;
  } else {
    return __builtin_bit_cast(float, __builtin_amdgcn_update_dpp(
        0, __builtin_bit_cast(int, x), 0x120 + K, 0xf, 0xf, true));
  }
}

// ---------------------------------------------------------------------------
// K2 v10: identical compute to round-6's measured-good 309us kernel; only
// changes: (a) h written in K4-friendly layout h_T[b][t][dir*128+k] (same
// store count & scatter granularity as before), (b) zeroes the loss
// accumulator so K4 can atomicAdd (K3 is gone).
// ---------------------------------------------------------------------------
__global__ __launch_bounds__(512, 2) void k2_lstm(
    const int* __restrict__ words, const float* __restrict__ emb,
    const float* __restrict__ Wih_f, const float* __restrict__ Whh_f,
    const float* __restrict__ bih_f, const float* __restrict__ bhh_f,
    const float* __restrict__ Wih_b, const float* __restrict__ Whh_b,
    const float* __restrict__ bih_b, const float* __restrict__ bhh_b,
    ushort_t* __restrict__ hT, float* __restrict__ loss_out) {
  const int wg = blockIdx.x;
  const int dir = wg >> 7;
  const int r0 = (wg & 127) << 1;
  if (wg == 0 && threadIdx.x == 0) loss_out[0] = 0.f;
  const float* Whh = dir ? Whh_b : Whh_f;
  const float* Wih = dir ? Wih_b : Wih_f;
  const float* bih = dir ? bih_b : bih_f;
  const float* bhh = dir ? bhh_b : bhh_f;

  const int tid = threadIdx.x;
  const int w = tid >> 6;        // wave 0..7
  const int lane = tid & 63;
  const int l15 = lane & 15;
  const int kq = lane >> 4;      // 0..3

  __shared__ __align__(16) ushort_t hx[2][2][136];      //  1,088 B
  __shared__ __align__(16) ushort_t xp[2][16][128][4];  // 32,768 B
  __shared__ __align__(16) ushort_t xs[2][16][136];     //  8,704 B

  // ---- register-resident weight fragments (bf16), [quadrant][K-chunk] ----
  bf16x8 wfh[4][4], wfx[4][4];
  float biasP[4];
#pragma unroll
  for (int Q = 0; Q < 4; ++Q) {
    const int n = Q * 128 + w * 16 + l15;
    biasP[Q] = bih[n] + bhh[n];
#pragma unroll
    for (int c = 0; c < 4; ++c) {
      const int k0 = c * 32 + kq * 8;
      const float* sh = Whh + n * 128 + k0;
      const float* sx = Wih + n * 128 + k0;
      wfh[Q][c] = pack8(*(const float4*)sh, *(const float4*)(sh + 4));
      wfx[Q][c] = pack8(*(const float4*)sx, *(const float4*)(sx + 4));
    }
  }

  const int ur = (lane >> 4) & 1;
  const int uj = w * 16 + l15;
  float cst = 0.f;
  const f32x4 fz = {0.f, 0.f, 0.f, 0.f};   // persistent MFMA C-init

  const int sm = tid >> 5;
  const int sc = (tid & 31) * 4;
  const int str = r0 + (sm & 1);
  const int stl = sm >> 1;

  uint_t pd0[4], pd1[4];
  f32x4 pc = {0.f, 0.f, 0.f, 0.f};
  f32x4 pcsv = {0.f, 0.f, 0.f, 0.f};

  // ---- prologue ----
  if (tid < 256) hx[0][tid >> 7][tid & 127] = 0;   // h(-1) = 0
  {  // stage xs[1] = x(block 0)
    const int tg = stl;
    const int tf = dir ? (511 - tg) : tg;
    const int word = words[str * 512 + tf];
    float4 av = *(const float4*)(emb + (size_t)word * 128 + sc);
    *(uint2*)&xs[1][sm][sc] = pack4(av);
  }
  WGBAR();
  {
    f32x4 qv[4];
#pragma unroll
    for (int Q = 0; Q < 4; ++Q) {
      f32x4 pc0 = {biasP[Q], biasP[Q], biasP[Q], biasP[Q]};
#pragma unroll
      for (int c = 0; c < 4; ++c) {
        bf16x8 af = __builtin_bit_cast(bf16x8, *(const uint4*)&xs[1][l15][kq * 8 + c * 32]);
        pc0 = __builtin_amdgcn_mfma_f32_16x16x32_bf16(af, wfx[Q][c], pc0, 0, 0, 0);
      }
      qv[Q] = pc0;
    }
#pragma unroll
    for (int rr = 0; rr < 4; ++rr) {
      pd0[rr] = cvtpk(qv[0][rr], qv[1][rr]);
      pd1[rr] = cvtpk(qv[2][rr], qv[3][rr]);
      *(uint2*)&xp[0][kq * 4 + rr][uj][0] = make_uint2(pd0[rr], pd1[rr]);
    }
  }
  {  // stage xs[0] = x(block 1)
    const int tg = 8 + stl;
    const int tf = dir ? (511 - tg) : tg;
    const int word = words[str * 512 + tf];
    float4 av = *(const float4*)(emb + (size_t)word * 128 + sc);
    *(uint2*)&xs[0][sm][sc] = pack4(av);
  }
  WGBAR();

  int sword = 0;
  float4 se0 = make_float4(0.f, 0.f, 0.f, 0.f);

#pragma unroll 1
  for (int i = 0; i < 64; ++i) {
    const int pcon = i & 1;
    const int ppro = pcon ^ 1;
    bf16x8 afp[4];
    if (i < 63) {
#pragma unroll
      for (int c = 0; c < 4; ++c)
        afp[c] = __builtin_bit_cast(bf16x8, *(const uint4*)&xs[pcon][l15][kq * 8 + c * 32]);
    }
#pragma unroll
    for (int s = 0; s < 8; ++s) {
      const int t = i * 8 + s;
      const int p = t & 1;
      const uint2 xq = *(const uint2*)&xp[pcon][2 * s + ur][uj][0];
      if (i < 62) {
        if (s == 0) {
          const int tg = (i + 2) * 8 + stl;
          const int tf = dir ? (511 - tg) : tg;
          sword = words[str * 512 + tf];
        }
        if (s == 2) se0 = *(const float4*)(emb + (size_t)sword * 128 + sc);
        if (s == 6) *(uint2*)&xs[ppro][sm][sc] = pack4(se0);
      }
      // ---- recurrence MFMAs ----
      f32x4 a0, a1, a2, a3;
      const ushort_t* abase = &hx[p][l15 & 1][kq * 8];
      {
        bf16x8 af = __builtin_bit_cast(bf16x8, *(const uint4*)(abase));
        a0 = __builtin_amdgcn_mfma_f32_16x16x32_bf16(af, wfh[0][0], fz, 0, 0, 0);
        a1 = __builtin_amdgcn_mfma_f32_16x16x32_bf16(af, wfh[1][0], fz, 0, 0, 0);
        a2 = __builtin_amdgcn_mfma_f32_16x16x32_bf16(af, wfh[2][0], fz, 0, 0, 0);
        a3 = __builtin_amdgcn_mfma_f32_16x16x32_bf16(af, wfh[3][0], fz, 0, 0, 0);
      }
#pragma unroll
      for (int c = 1; c < 4; ++c) {
        bf16x8 af = __builtin_bit_cast(bf16x8, *(const uint4*)(abase + c * 32));
        a0 = __builtin_amdgcn_mfma_f32_16x16x32_bf16(af, wfh[0][c], a0, 0, 0, 0);
        a1 = __builtin_amdgcn_mfma_f32_16x16x32_bf16(af, wfh[1][c], a1, 0, 0, 0);
        a2 = __builtin_amdgcn_mfma_f32_16x16x32_bf16(af, wfh[2][c], a2, 0, 0, 0);
        a3 = __builtin_amdgcn_mfma_f32_16x16x32_bf16(af, wfh[3][c], a3, 0, 0, 0);
      }
      // ---- production MFMAs for block i+1 ----
      if (i < 63) {
        const int Q = s >> 1;
        if ((s & 1) == 0) {
          pc = f32x4{biasP[Q], biasP[Q], biasP[Q], biasP[Q]};
          pc = __builtin_amdgcn_mfma_f32_16x16x32_bf16(afp[0], wfx[Q][0], pc, 0, 0, 0);
          pc = __builtin_amdgcn_mfma_f32_16x16x32_bf16(afp[1], wfx[Q][1], pc, 0, 0, 0);
        } else {
          pc = __builtin_amdgcn_mfma_f32_16x16x32_bf16(afp[2], wfx[Q][2], pc, 0, 0, 0);
          pc = __builtin_amdgcn_mfma_f32_16x16x32_bf16(afp[3], wfx[Q][3], pc, 0, 0, 0);
          if ((s & 2) == 0) {
            pcsv = pc;
          } else if (s == 3) {
#pragma unroll
            for (int rr = 0; rr < 4; ++rr) pd0[rr] = cvtpk(pcsv[rr], pc[rr]);
          } else {
#pragma unroll
            for (int rr = 0; rr < 4; ++rr) {
              pd1[rr] = cvtpk(pcsv[rr], pc[rr]);
              *(uint2*)&xp[ppro][kq * 4 + rr][uj][0] = make_uint2(pd0[rr], pd1[rr]);
            }
          }
        }
      }
      // ---- gates ----
      const float g0 = (ur ? a0[1] : a0[0]) + __builtin_bit_cast(float, xq.x << 16);
      const float g1 = (ur ? a1[1] : a1[0]) + __builtin_bit_cast(float, xq.x & 0xffff0000u);
      const float g2 = (ur ? a2[1] : a2[0]) + __builtin_bit_cast(float, xq.y << 16);
      const float g3 = (ur ? a3[1] : a3[0]) + __builtin_bit_cast(float, xq.y & 0xffff0000u);
      const float si = sigm(g0), sf = sigm(g1), so = sigm(g3);
      const float tg = tanha(g2);
      cst = sf * cst + si * tg;
      const float h = so * tanha(cst);
      const ushort_t hb = (ushort_t)cvtpk(h, h);
      if (lane < 32) {
        hx[p ^ 1][ur][uj] = hb;
        const int tf = dir ? (511 - t) : t;
        // h_T[b][t][dir*128 + k] layout for K4's MFMA A-fragments
        hT[((size_t)(r0 + ur) * 512 + tf) * 256 + (dir << 7) + uj] = hb;
      }
      WGBAR();
    }
  }
}

// ---------------------------------------------------------------------------
// K4 v12 "fused": one block per batch row b, 2 waves. 8 phases of 64 steps:
//   phase p: [both waves] produce emis tile p+1 (h_T @ Wout^T + bout via
//            16x16x32 MFMA) into LDS double-buffer; __syncthreads();
//            wave0: 64 serial CRF steps (emis from LDS -- ZERO global loads
//            in the serial loop); wave1: numerator for tile p (from LDS,
//            runs inside wave0's serial phase -- previously idle time);
//            __syncthreads();
// Kills: k3 kernel, 25MB emis HBM roundtrip, 64MB strided h re-read, 1 gap.
// CRF math is the bit-identical v11 sequence (named-reg pipeline retained;
// reload distance 7 steps >> LDS latency). emis rounding differs slightly
// from k3 (16x16x32 vs 32x32x16 summation order).
// ---------------------------------------------------------------------------
#define K4_ROW(OP, m) \
  OP(m, 0) OP(m, 1) OP(m, 2) OP(m, 3) OP(m, 4) OP(m, 5) OP(m, 6) OP(m, 7) \
  OP(m, 8) OP(m, 9) OP(m, 10) OP(m, 11) OP(m, 12) OP(m, 13) OP(m, 14) OP(m, 15)
#define K4_ALL(OP) K4_ROW(OP, 0) K4_ROW(OP, 1) K4_ROW(OP, 2) K4_ROW(OP, 3)

#define ROTMOD_0  ""
#define ROTMOD_1  "row_ror:1 row_mask:0xf bank_mask:0xf"
#define ROTMOD_2  "row_ror:2 row_mask:0xf bank_mask:0xf"
#define ROTMOD_3  "row_ror:3 row_mask:0xf bank_mask:0xf"
#define ROTMOD_4  "row_ror:4 row_mask:0xf bank_mask:0xf"
#define ROTMOD_5  "row_ror:5 row_mask:0xf bank_mask:0xf"
#define ROTMOD_6  "row_ror:6 row_mask:0xf bank_mask:0xf"
#define ROTMOD_7  "row_ror:7 row_mask:0xf bank_mask:0xf"
#define ROTMOD_8  "row_ror:8 row_mask:0xf bank_mask:0xf"
#define ROTMOD_9  "row_ror:9 row_mask:0xf bank_mask:0xf"
#define ROTMOD_10 "row_ror:10 row_mask:0xf bank_mask:0xf"
#define ROTMOD_11 "row_ror:11 row_mask:0xf bank_mask:0xf"
#define ROTMOD_12 "row_ror:12 row_mask:0xf bank_mask:0xf"
#define ROTMOD_13 "row_ror:13 row_mask:0xf bank_mask:0xf"
#define ROTMOD_14 "row_ror:14 row_mask:0xf bank_mask:0xf"
#define ROTMOD_15 "row_ror:15 row_mask:0xf bank_mask:0xf"

#define K4_FMA(m_, k_) asm( \
    "v_fmac_f32 %0, %1, %2 " ROTMOD_##k_ \
    : "+v"(acc[((m_) * 16 + (k_)) & 7]) \
    : "v"(dm[m_]), "v"(pcr[(m_) * 16 + (k_)]));

#define K4_BODY(FOLD, LOADSTMT, ENSRC, MBIT, MEAS)                            \
  {                                                                           \
    float E = Ecur;                                                           \
    int eApp = 0;                                                             \
    if (FOLD) {                                                               \
      const float sc_ =                                                       \
          __builtin_bit_cast(float, (uint_t)(127 - e_pend) << 23);            \
      E *= sc_;                                                               \
      eApp = e_pend;                                                          \
    }                                                                         \
    LOADSTMT;                                                                 \
    const float En = fexp2((ENSRC) * L2E);                                    \
    float dm[4];                                                              \
    dm[0] = d;                                                                \
    dm[1] = __shfl_xor(d, 16, 64);                                            \
    dm[2] = __shfl_xor(d, 32, 64);                                            \
    dm[3] = __shfl_xor(d, 48, 64);                                            \
    float acc[8] = {0.f, 0.f, 0.f, 0.f, 0.f, 0.f, 0.f, 0.f};                  \
    K4_ALL(K4_FMA)                                                            \
    const float nxt = (((acc[0] + acc[1]) + (acc[2] + acc[3])) +              \
                       ((acc[4] + acc[5]) + (acc[6] + acc[7]))) * E;          \
    if (MBIT) {                                                               \
      d = v ? nxt : 0.f;                                                      \
      S += eApp;                                                              \
    }                                                                         \
    if (MEAS) {                                                               \
      const int db_ =                                                         \
          __builtin_amdgcn_readfirstlane(__builtin_bit_cast(int, d));         \
      e_pend = ((db_ >> 23) & 0xff) - 127;                                    \
    }                                                                         \
    Ecur = En;                                                                \
  }

// emis from LDS (row-padded to 50 floats: conflict-free produce writes)
#define EMLDS(tt) emis_t[((tt) >> 6) & 1][(tt) & 63][jj]

__global__ __launch_bounds__(128, 1) void k4_fused(
    const int* __restrict__ words, const int* __restrict__ tags,
    const ushort_t* __restrict__ hT, const float* __restrict__ Wout,
    const float* __restrict__ bout, const float* __restrict__ trans,
    const float* __restrict__ st, const float* __restrict__ et,
    float* __restrict__ out) {
  const int b = blockIdx.x;
  const int tid = threadIdx.x;
  const int wv = tid >> 6;       // wave 0 = CRF, wave 1 = numerator
  const int lane = tid & 63;
  const int l15 = lane & 15;
  const int kq = lane >> 4;

  __shared__ __align__(16) ushort_t wfrag[3][8][64][8];  // 24,576 B
  __shared__ float emis_t[2][64][50];                    // 25,600 B
  __shared__ float res[2];

  const ushort_t* hb_base = hT + (size_t)b * 512 * 256;

  // ---- build Wout B-fragments (pre-swizzled, one b128 per use) + bias ----
  float bo3[3];
#pragma unroll
  for (int jt = 0; jt < 3; ++jt) bo3[jt] = bout[jt * 16 + l15];
#pragma unroll 1
  for (int f = wv; f < 24; f += 2) {
    const int jt = f >> 3, c = f & 7;
    const float* src = Wout + (jt * 16 + l15) * 256 + c * 32 + kq * 8;
    bf16x8 fr = pack8(*(const float4*)src, *(const float4*)(src + 4));
    *(uint4*)&wfrag[jt][c][lane][0] = __builtin_bit_cast(uint4, fr);
  }

  // ---- per-wave pre-work (no barriers inside) ----
  const int j = lane;
  const bool v = j < 48;
  const int jj = v ? j : 47;
  float pcr[64];
  unsigned long long mb0, mb1, mb2, mb3, mb4, mb5, mb6, mb7;
  float s_num = 0.f;
  int cnt = 0;
  if (wv == 0) {
    // self-calibration of the DPP gather (semantics-proof)
    float pm[4];
    const float pj = (float)j;
    pm[0] = pj;
    pm[1] = __shfl_xor(pj, 16, 64);
    pm[2] = __shfl_xor(pj, 32, 64);
    pm[3] = __shfl_xor(pj, 48, 64);
#define K4_CAL(m, k) { const int idx_ = (int)rotk<k>(pm[m]); \
    pcr[(m) * 16 + (k)] = (v && idx_ < 48) ? fexp2(trans[idx_ * 48 + j] * L2E) : 0.f; }
    K4_ALL(K4_CAL)
#undef K4_CAL
    mb0 = __ballot(words[b * 512 + 0 * 64 + j] != 0);
    mb1 = __ballot(words[b * 512 + 1 * 64 + j] != 0);
    mb2 = __ballot(words[b * 512 + 2 * 64 + j] != 0);
    mb3 = __ballot(words[b * 512 + 3 * 64 + j] != 0);
    mb4 = __ballot(words[b * 512 + 4 * 64 + j] != 0);
    mb5 = __ballot(words[b * 512 + 5 * 64 + j] != 0);
    mb6 = __ballot(words[b * 512 + 6 * 64 + j] != 0);
    mb7 = __ballot(words[b * 512 + 7 * 64 + j] != 0);
  }
  __syncthreads();   // wfrag ready

  // ---- produce one 64-t emis tile: wave wv handles t-subtiles wv*2, wv*2+1
  auto produce = [&](int tile) {
    const int t0 = tile * 64;
    const int buf = tile & 1;
#pragma unroll
    for (int tsn = 0; tsn < 2; ++tsn) {
      const int ts = wv * 2 + tsn;
      const int tt0 = t0 + ts * 16;
      bf16x8 afr[8];
#pragma unroll
      for (int c = 0; c < 8; ++c)
        afr[c] = __builtin_bit_cast(bf16x8,
            *(const uint4*)(hb_base + (size_t)(tt0 + l15) * 256 + c * 32 + kq * 8));
#pragma unroll
      for (int jt = 0; jt < 3; ++jt) {
        f32x4 acc2 = {bo3[jt], bo3[jt], bo3[jt], bo3[jt]};
#pragma unroll
        for (int c = 0; c < 8; ++c) {
          bf16x8 bfr = __builtin_bit_cast(bf16x8, *(const uint4*)&wfrag[jt][c][lane][0]);
          acc2 = __builtin_amdgcn_mfma_f32_16x16x32_bf16(afr[c], bfr, acc2, 0, 0, 0);
        }
#pragma unroll
        for (int r = 0; r < 4; ++r)
          emis_t[buf][ts * 16 + kq * 4 + r][jt * 16 + l15] = acc2[r];
      }
    }
  };

  produce(0);
  __syncthreads();   // tile 0 ready

  // CRF state (wave 0)
  float d = 0.f, Ecur = 0.f;
  int S = 0, e_pend = 0;
  float pm_0, pm_1, pm_2, pm_3, pm_4, pm_5, pm_6;
  float em_0, em_1, em_2, em_3, em_4, em_5, em_6, em_7;

#pragma unroll 1
  for (int p = 0; p < 8; ++p) {
    if (p < 7) produce(p + 1);
    __syncthreads();   // tile p+1 ready; tile p stable
    if (wv == 0) {
      // ---- wave 0: 64 serial CRF steps, emis from LDS ----
      const unsigned long long mq =
          p == 0 ? mb0 : p == 1 ? mb1 : p == 2 ? mb2 : p == 3 ? mb3 :
          p == 4 ? mb4 : p == 5 ? mb5 : p == 6 ? mb6 : mb7;
      if (p == 0) {
        d = v ? fexp2((st[j] + EMLDS(0)) * L2E) : 0.f;
        pm_0 = EMLDS(1); pm_1 = EMLDS(2); pm_2 = EMLDS(3); pm_3 = EMLDS(4);
        pm_4 = EMLDS(5); pm_5 = EMLDS(6); pm_6 = EMLDS(7);
        em_0 = EMLDS(8);  em_1 = EMLDS(9);  em_2 = EMLDS(10); em_3 = EMLDS(11);
        em_4 = EMLDS(12); em_5 = EMLDS(13); em_6 = EMLDS(14); em_7 = EMLDS(15);
        Ecur = fexp2(pm_0 * L2E);
        const uint_t mm = (uint_t)mq;
        K4_BODY(false, (void)0, pm_1, (mm >> 1) & 1u, false)
        K4_BODY(true,  (void)0, pm_2, (mm >> 2) & 1u, false)
        K4_BODY(false, (void)0, pm_3, (mm >> 3) & 1u, false)
        K4_BODY(false, (void)0, pm_4, (mm >> 4) & 1u, false)
        K4_BODY(false, (void)0, pm_5, (mm >> 5) & 1u, false)
        K4_BODY(false, (void)0, pm_6, (mm >> 6) & 1u, false)
        K4_BODY(false, (void)0, em_0, (mm >> 7) & 1u, false)
      }
#pragma unroll 1
      for (int gi = (p == 0 ? 1 : 0); gi < 8; ++gi) {
        const int G = p * 64 + gi * 8;
        const uint_t mm = (uint_t)(mq >> (gi * 8));
        const int Lb = G + 8;
        K4_BODY(false, em_0 = EMLDS(min(511, Lb + 0)), em_1, (mm >> 0) & 1u, true)
        K4_BODY(false, em_1 = EMLDS(min(511, Lb + 1)), em_2, (mm >> 1) & 1u, false)
        K4_BODY(true,  em_2 = EMLDS(min(511, Lb + 2)), em_3, (mm >> 2) & 1u, false)
        K4_BODY(false, em_3 = EMLDS(min(511, Lb + 3)), em_4, (mm >> 3) & 1u, false)
        K4_BODY(false, em_4 = EMLDS(min(511, Lb + 4)), em_5, (mm >> 4) & 1u, false)
        K4_BODY(false, em_5 = EMLDS(min(511, Lb + 5)), em_6, (mm >> 5) & 1u, false)
        K4_BODY(false, em_6 = EMLDS(min(511, Lb + 6)), em_7, (mm >> 6) & 1u, false)
        K4_BODY(false, em_7 = EMLDS(min(511, Lb + 7)), em_0, (mm >> 7) & 1u, false)
      }
    } else {
      // ---- wave 1: numerator for tile p (lane = t within tile) ----
      const int t = p * 64 + lane;
      const int wvd = words[b * 512 + t];
      const int tg = tags[b * 512 + t];
      const bool mt = (wvd != 0);
      cnt += mt ? 1 : 0;
      if (t == 0) {
        s_num += st[tg] + emis_t[0][0][tg];
      } else if (mt) {
        const int tp = tags[b * 512 + t - 1];
        s_num += trans[tp * 48 + tg] + emis_t[p & 1][t & 63][tg];
      }
    }
    __syncthreads();   // tile p consumed; buffer may be overwritten
  }

  // ---- epilogue ----
  if (wv == 0) {
    float uf = v ? d * fexp2(et[j] * L2E) : 0.f;
#pragma unroll
    for (int dd = 32; dd; dd >>= 1) uf += __shfl_xor(uf, dd, 64);
    if (j == 0) res[0] = ((float)S + flog2(uf)) * LN2;
  } else {
#pragma unroll
    for (int dd = 32; dd; dd >>= 1) {
      s_num += __shfl_xor(s_num, dd, 64);
      cnt += __shfl_xor(cnt, dd, 64);
    }
    if (lane == 0) {
      const int lt = tags[b * 512 + cnt - 1];
      res[1] = s_num + et[lt];
    }
  }
  __syncthreads();
  // loss = -mean(num - denom)  ->  accumulate (denom - num)/256
  if (tid == 0) atomicAdd(out, (res[0] - res[1]) * (1.0f / 256.0f));
}

// ---------------------------------------------------------------------------
extern "C" void kernel_launch(void* const* d_in, const int* in_sizes, int n_in,
                              void* d_out, int out_size, void* d_ws, size_t ws_size,
                              hipStream_t stream) {
  (void)in_sizes; (void)n_in; (void)out_size; (void)ws_size;
  const int*   words = (const int*)d_in[0];
  const int*   tags  = (const int*)d_in[1];
  // d_in[2] = mask (bool) -- unused; reconstructed as words != 0
  const float* emb   = (const float*)d_in[3];
  const float* Wih_f = (const float*)d_in[4];
  const float* Whh_f = (const float*)d_in[5];
  const float* bih_f = (const float*)d_in[6];
  const float* bhh_f = (const float*)d_in[7];
  const float* Wih_b = (const float*)d_in[8];
  const float* Whh_b = (const float*)d_in[9];
  const float* bih_b = (const float*)d_in[10];
  const float* bhh_b = (const float*)d_in[11];
  const float* Wout  = (const float*)d_in[12];
  const float* bout  = (const float*)d_in[13];
  const float* trans = (const float*)d_in[14];
  const float* st    = (const float*)d_in[15];
  const float* et    = (const float*)d_in[16];

  char* ws = (char*)d_ws;
  ushort_t* h_T = (ushort_t*)(ws);   // [256 b][512 t][256 k] bf16 = 64 MB

  k2_lstm  <<<256, 512, 0, stream>>>(words, emb,
                                     Wih_f, Whh_f, bih_f, bhh_f,
                                     Wih_b, Whh_b, bih_b, bhh_b,
                                     h_T, (float*)d_out);
  k4_fused <<<256, 128, 0, stream>>>(words, tags, h_T, Wout, bout,
                                     trans, st, et, (float*)d_out);
}

// Round 10
// 447.479 us; speedup vs baseline: 1.8555x; 1.1199x over previous
//
#include <hip/hip_runtime.h>
#include <hip/hip_bf16.h>

// Sizes (fixed by the reference)
//  V=32000, T=48, E=128, HID=256, H=128, B=256, L=512, 4H=512
typedef unsigned short ushort_t;
typedef unsigned int uint_t;
typedef __bf16 bf16x8 __attribute__((ext_vector_type(8)));
typedef float f32x4 __attribute__((ext_vector_type(4)));

#define L2E 1.44269504088896340736f
#define LN2 0.69314718055994530942f

// LDS-only barrier: does NOT drain vmcnt -> global loads/stores stay in flight.
#define WGBAR() __asm__ volatile("s_waitcnt lgkmcnt(0)\n\ts_barrier" ::: "memory")

static __device__ __forceinline__ float fexp2(float x) { return __builtin_amdgcn_exp2f(x); }
static __device__ __forceinline__ float flog2(float x) { return __builtin_amdgcn_logf(x); }
static __device__ __forceinline__ float frcp (float x) { return __builtin_amdgcn_rcpf(x); }

static __device__ __forceinline__ float sigm(float x) {
  return frcp(1.0f + fexp2(-L2E * x));
}
static __device__ __forceinline__ float tanha(float x) {
  return 1.0f - 2.0f * frcp(1.0f + fexp2(2.0f * L2E * x));
}

// Hardware bf16 pair-convert (RNE). result = bf16(lo) | bf16(hi)<<16.
static __device__ __forceinline__ uint_t cvtpk(float lo, float hi) {
  uint_t r;
  asm("v_cvt_pk_bf16_f32 %0, %1, %2" : "=v"(r) : "v"(lo), "v"(hi));
  return r;
}
static __device__ __forceinline__ bf16x8 pack8(float4 a, float4 b) {
  uint4 u = make_uint4(cvtpk(a.x, a.y), cvtpk(a.z, a.w),
                       cvtpk(b.x, b.y), cvtpk(b.z, b.w));
  return __builtin_bit_cast(bf16x8, u);
}
static __device__ __forceinline__ uint2 pack4(float4 a) {
  return make_uint2(cvtpk(a.x, a.y), cvtpk(a.z, a.w));
}

// DPP row-rotate-right by K within 16-lane rows (K=0 -> identity).
template <int K>
static __device__ __forceinline__ float rotk(float x) {
  if constexpr (K == 0) {
    return x;
  } else {
    return __builtin_bit_cast(float, __builtin_amdgcn_update_dpp(
        0, __builtin_bit_cast(int, x), 0x120 + K, 0xf, 0xf, true));
  }
}

// ---------------------------------------------------------------------------
// K2 v10 (unchanged from round 9 -- measured-good ~310 us).
// ---------------------------------------------------------------------------
__global__ __launch_bounds__(512, 2) void k2_lstm(
    const int* __restrict__ words, const float* __restrict__ emb,
    const float* __restrict__ Wih_f, const float* __restrict__ Whh_f,
    const float* __restrict__ bih_f, const float* __restrict__ bhh_f,
    const float* __restrict__ Wih_b, const float* __restrict__ Whh_b,
    const float* __restrict__ bih_b, const float* __restrict__ bhh_b,
    ushort_t* __restrict__ hT, float* __restrict__ loss_out) {
  const int wg = blockIdx.x;
  const int dir = wg >> 7;
  const int r0 = (wg & 127) << 1;
  if (wg == 0 && threadIdx.x == 0) loss_out[0] = 0.f;
  const float* Whh = dir ? Whh_b : Whh_f;
  const float* Wih = dir ? Wih_b : Wih_f;
  const float* bih = dir ? bih_b : bih_f;
  const float* bhh = dir ? bhh_b : bhh_f;

  const int tid = threadIdx.x;
  const int w = tid >> 6;        // wave 0..7
  const int lane = tid & 63;
  const int l15 = lane & 15;
  const int kq = lane >> 4;      // 0..3

  __shared__ __align__(16) ushort_t hx[2][2][136];      //  1,088 B
  __shared__ __align__(16) ushort_t xp[2][16][128][4];  // 32,768 B
  __shared__ __align__(16) ushort_t xs[2][16][136];     //  8,704 B

  bf16x8 wfh[4][4], wfx[4][4];
  float biasP[4];
#pragma unroll
  for (int Q = 0; Q < 4; ++Q) {
    const int n = Q * 128 + w * 16 + l15;
    biasP[Q] = bih[n] + bhh[n];
#pragma unroll
    for (int c = 0; c < 4; ++c) {
      const int k0 = c * 32 + kq * 8;
      const float* sh = Whh + n * 128 + k0;
      const float* sx = Wih + n * 128 + k0;
      wfh[Q][c] = pack8(*(const float4*)sh, *(const float4*)(sh + 4));
      wfx[Q][c] = pack8(*(const float4*)sx, *(const float4*)(sx + 4));
    }
  }

  const int ur = (lane >> 4) & 1;
  const int uj = w * 16 + l15;
  float cst = 0.f;
  const f32x4 fz = {0.f, 0.f, 0.f, 0.f};

  const int sm = tid >> 5;
  const int sc = (tid & 31) * 4;
  const int str = r0 + (sm & 1);
  const int stl = sm >> 1;

  uint_t pd0[4], pd1[4];
  f32x4 pc = {0.f, 0.f, 0.f, 0.f};
  f32x4 pcsv = {0.f, 0.f, 0.f, 0.f};

  if (tid < 256) hx[0][tid >> 7][tid & 127] = 0;
  {
    const int tg = stl;
    const int tf = dir ? (511 - tg) : tg;
    const int word = words[str * 512 + tf];
    float4 av = *(const float4*)(emb + (size_t)word * 128 + sc);
    *(uint2*)&xs[1][sm][sc] = pack4(av);
  }
  WGBAR();
  {
    f32x4 qv[4];
#pragma unroll
    for (int Q = 0; Q < 4; ++Q) {
      f32x4 pc0 = {biasP[Q], biasP[Q], biasP[Q], biasP[Q]};
#pragma unroll
      for (int c = 0; c < 4; ++c) {
        bf16x8 af = __builtin_bit_cast(bf16x8, *(const uint4*)&xs[1][l15][kq * 8 + c * 32]);
        pc0 = __builtin_amdgcn_mfma_f32_16x16x32_bf16(af, wfx[Q][c], pc0, 0, 0, 0);
      }
      qv[Q] = pc0;
    }
#pragma unroll
    for (int rr = 0; rr < 4; ++rr) {
      pd0[rr] = cvtpk(qv[0][rr], qv[1][rr]);
      pd1[rr] = cvtpk(qv[2][rr], qv[3][rr]);
      *(uint2*)&xp[0][kq * 4 + rr][uj][0] = make_uint2(pd0[rr], pd1[rr]);
    }
  }
  {
    const int tg = 8 + stl;
    const int tf = dir ? (511 - tg) : tg;
    const int word = words[str * 512 + tf];
    float4 av = *(const float4*)(emb + (size_t)word * 128 + sc);
    *(uint2*)&xs[0][sm][sc] = pack4(av);
  }
  WGBAR();

  int sword = 0;
  float4 se0 = make_float4(0.f, 0.f, 0.f, 0.f);

#pragma unroll 1
  for (int i = 0; i < 64; ++i) {
    const int pcon = i & 1;
    const int ppro = pcon ^ 1;
    bf16x8 afp[4];
    if (i < 63) {
#pragma unroll
      for (int c = 0; c < 4; ++c)
        afp[c] = __builtin_bit_cast(bf16x8, *(const uint4*)&xs[pcon][l15][kq * 8 + c * 32]);
    }
#pragma unroll
    for (int s = 0; s < 8; ++s) {
      const int t = i * 8 + s;
      const int p = t & 1;
      const uint2 xq = *(const uint2*)&xp[pcon][2 * s + ur][uj][0];
      if (i < 62) {
        if (s == 0) {
          const int tg = (i + 2) * 8 + stl;
          const int tf = dir ? (511 - tg) : tg;
          sword = words[str * 512 + tf];
        }
        if (s == 2) se0 = *(const float4*)(emb + (size_t)sword * 128 + sc);
        if (s == 6) *(uint2*)&xs[ppro][sm][sc] = pack4(se0);
      }
      f32x4 a0, a1, a2, a3;
      const ushort_t* abase = &hx[p][l15 & 1][kq * 8];
      {
        bf16x8 af = __builtin_bit_cast(bf16x8, *(const uint4*)(abase));
        a0 = __builtin_amdgcn_mfma_f32_16x16x32_bf16(af, wfh[0][0], fz, 0, 0, 0);
        a1 = __builtin_amdgcn_mfma_f32_16x16x32_bf16(af, wfh[1][0], fz, 0, 0, 0);
        a2 = __builtin_amdgcn_mfma_f32_16x16x32_bf16(af, wfh[2][0], fz, 0, 0, 0);
        a3 = __builtin_amdgcn_mfma_f32_16x16x32_bf16(af, wfh[3][0], fz, 0, 0, 0);
      }
#pragma unroll
      for (int c = 1; c < 4; ++c) {
        bf16x8 af = __builtin_bit_cast(bf16x8, *(const uint4*)(abase + c * 32));
        a0 = __builtin_amdgcn_mfma_f32_16x16x32_bf16(af, wfh[0][c], a0, 0, 0, 0);
        a1 = __builtin_amdgcn_mfma_f32_16x16x32_bf16(af, wfh[1][c], a1, 0, 0, 0);
        a2 = __builtin_amdgcn_mfma_f32_16x16x32_bf16(af, wfh[2][c], a2, 0, 0, 0);
        a3 = __builtin_amdgcn_mfma_f32_16x16x32_bf16(af, wfh[3][c], a3, 0, 0, 0);
      }
      if (i < 63) {
        const int Q = s >> 1;
        if ((s & 1) == 0) {
          pc = f32x4{biasP[Q], biasP[Q], biasP[Q], biasP[Q]};
          pc = __builtin_amdgcn_mfma_f32_16x16x32_bf16(afp[0], wfx[Q][0], pc, 0, 0, 0);
          pc = __builtin_amdgcn_mfma_f32_16x16x32_bf16(afp[1], wfx[Q][1], pc, 0, 0, 0);
        } else {
          pc = __builtin_amdgcn_mfma_f32_16x16x32_bf16(afp[2], wfx[Q][2], pc, 0, 0, 0);
          pc = __builtin_amdgcn_mfma_f32_16x16x32_bf16(afp[3], wfx[Q][3], pc, 0, 0, 0);
          if ((s & 2) == 0) {
            pcsv = pc;
          } else if (s == 3) {
#pragma unroll
            for (int rr = 0; rr < 4; ++rr) pd0[rr] = cvtpk(pcsv[rr], pc[rr]);
          } else {
#pragma unroll
            for (int rr = 0; rr < 4; ++rr) {
              pd1[rr] = cvtpk(pcsv[rr], pc[rr]);
              *(uint2*)&xp[ppro][kq * 4 + rr][uj][0] = make_uint2(pd0[rr], pd1[rr]);
            }
          }
        }
      }
      const float g0 = (ur ? a0[1] : a0[0]) + __builtin_bit_cast(float, xq.x << 16);
      const float g1 = (ur ? a1[1] : a1[0]) + __builtin_bit_cast(float, xq.x & 0xffff0000u);
      const float g2 = (ur ? a2[1] : a2[0]) + __builtin_bit_cast(float, xq.y << 16);
      const float g3 = (ur ? a3[1] : a3[0]) + __builtin_bit_cast(float, xq.y & 0xffff0000u);
      const float si = sigm(g0), sf = sigm(g1), so = sigm(g3);
      const float tg = tanha(g2);
      cst = sf * cst + si * tg;
      const float h = so * tanha(cst);
      const ushort_t hb = (ushort_t)cvtpk(h, h);
      if (lane < 32) {
        hx[p ^ 1][ur][uj] = hb;
        const int tf = dir ? (511 - t) : t;
        hT[((size_t)(r0 + ur) * 512 + tf) * 256 + (dir << 7) + uj] = hb;
      }
      WGBAR();
    }
  }
}

// ---------------------------------------------------------------------------
// K4 v13: split-chain fused CRF. Linear algebra: with M_t = P.diag(E_t)
// (I when masked), denom = log(u^T . prod M_t . w), u = exp(st+em_0),
// w = exp(et). Split at t=256: wave0 computes x^T = u^T.M_L forward over
// t=1..255 (input spec: lengths>=256 -> NO masks below 256); wave1 computes
// y = M_R.w backward over t=511..256 (y <- P @ (E_t o y), masked skip,
// coefficients P[j][i] via the same self-calibrated gather). The two
// 256-step serial chains run CONCURRENTLY -> serial wall halves.
// denom = (S_a + S_b + log2(sum_j x_j y_j)) * ln2. Per phase: produce
// emis tiles for both ends (A:0->3 fwd, B:7->4 bwd, double-buffered per
// side) + numerator terms, then barrier, then 64 serial steps per chain.
// ---------------------------------------------------------------------------
#define K4_ROW(OP, m) \
  OP(m, 0) OP(m, 1) OP(m, 2) OP(m, 3) OP(m, 4) OP(m, 5) OP(m, 6) OP(m, 7) \
  OP(m, 8) OP(m, 9) OP(m, 10) OP(m, 11) OP(m, 12) OP(m, 13) OP(m, 14) OP(m, 15)
#define K4_ALL(OP) K4_ROW(OP, 0) K4_ROW(OP, 1) K4_ROW(OP, 2) K4_ROW(OP, 3)

#define ROTMOD_0  ""
#define ROTMOD_1  "row_ror:1 row_mask:0xf bank_mask:0xf"
#define ROTMOD_2  "row_ror:2 row_mask:0xf bank_mask:0xf"
#define ROTMOD_3  "row_ror:3 row_mask:0xf bank_mask:0xf"
#define ROTMOD_4  "row_ror:4 row_mask:0xf bank_mask:0xf"
#define ROTMOD_5  "row_ror:5 row_mask:0xf bank_mask:0xf"
#define ROTMOD_6  "row_ror:6 row_mask:0xf bank_mask:0xf"
#define ROTMOD_7  "row_ror:7 row_mask:0xf bank_mask:0xf"
#define ROTMOD_8  "row_ror:8 row_mask:0xf bank_mask:0xf"
#define ROTMOD_9  "row_ror:9 row_mask:0xf bank_mask:0xf"
#define ROTMOD_10 "row_ror:10 row_mask:0xf bank_mask:0xf"
#define ROTMOD_11 "row_ror:11 row_mask:0xf bank_mask:0xf"
#define ROTMOD_12 "row_ror:12 row_mask:0xf bank_mask:0xf"
#define ROTMOD_13 "row_ror:13 row_mask:0xf bank_mask:0xf"
#define ROTMOD_14 "row_ror:14 row_mask:0xf bank_mask:0xf"
#define ROTMOD_15 "row_ror:15 row_mask:0xf bank_mask:0xf"

#define K4_FMA(m_, k_) asm( \
    "v_fmac_f32 %0, %1, %2 " ROTMOD_##k_ \
    : "+v"(acc[((m_) * 16 + (k_)) & 7]) \
    : "v"(dm[m_]), "v"(pcr[(m_) * 16 + (k_)]));

// emis tile access (A: tile p in tA[p&1]; B: tile tau in tB[(tau&1)^1])
#define EMA(tt) tA[((tt) >> 6) & 1][(tt) & 63][jj]
#define EMB(tt) tB[((((tt) >> 6) & 1)) ^ 1][(tt) & 63][jj]

// forward step (no masks: t<256 always active per input spec lengths>=256)
#define A_BODY(FOLD, TN, MEAS)                                                \
  {                                                                           \
    float E = Ecur;                                                           \
    if (FOLD) {                                                               \
      E *= __builtin_bit_cast(float, (uint_t)(127 - e_pend) << 23);           \
      S += e_pend;                                                            \
    }                                                                         \
    const float emn_ = EMA(TN);                                               \
    float dm[4];                                                              \
    dm[0] = d;                                                                \
    dm[1] = __shfl_xor(d, 16, 64);                                            \
    dm[2] = __shfl_xor(d, 32, 64);                                            \
    dm[3] = __shfl_xor(d, 48, 64);                                            \
    float acc[8] = {0.f, 0.f, 0.f, 0.f, 0.f, 0.f, 0.f, 0.f};                  \
    K4_ALL(K4_FMA)                                                            \
    d = (((acc[0] + acc[1]) + (acc[2] + acc[3])) +                            \
         ((acc[4] + acc[5]) + (acc[6] + acc[7]))) * E;                        \
    if (MEAS) {                                                               \
      const int db_ =                                                         \
          __builtin_amdgcn_readfirstlane(__builtin_bit_cast(int, d));         \
      e_pend = ((db_ >> 23) & 0xff) - 127;                                    \
    }                                                                         \
    Ecur = fexp2(emn_ * L2E);                                                 \
  }

// backward step: d(=y) <- P @ (E_t o y) when masked-in
#define B_BODY(FOLD, TN, MBIT, MEAS)                                          \
  {                                                                           \
    float E = Ecur;                                                           \
    int eApp = 0;                                                             \
    if (FOLD) {                                                               \
      E *= __builtin_bit_cast(float, (uint_t)(127 - e_pend) << 23);           \
      eApp = e_pend;                                                          \
    }                                                                         \
    const float emn_ = EMB(TN);                                               \
    const float vs = E * d;                                                   \
    float dm[4];                                                              \
    dm[0] = vs;                                                               \
    dm[1] = __shfl_xor(vs, 16, 64);                                           \
    dm[2] = __shfl_xor(vs, 32, 64);                                           \
    dm[3] = __shfl_xor(vs, 48, 64);                                           \
    float acc[8] = {0.f, 0.f, 0.f, 0.f, 0.f, 0.f, 0.f, 0.f};                  \
    K4_ALL(K4_FMA)                                                            \
    const float nxt = (((acc[0] + acc[1]) + (acc[2] + acc[3])) +              \
                       ((acc[4] + acc[5]) + (acc[6] + acc[7])));              \
    if (MBIT) { d = nxt; S += eApp; }                                         \
    if (MEAS) {                                                               \
      const int db_ =                                                         \
          __builtin_amdgcn_readfirstlane(__builtin_bit_cast(int, d));         \
      e_pend = ((db_ >> 23) & 0xff) - 127;                                    \
    }                                                                         \
    Ecur = fexp2(emn_ * L2E);                                                 \
  }

__global__ __launch_bounds__(128, 1) void k4_fused(
    const int* __restrict__ words, const int* __restrict__ tags,
    const ushort_t* __restrict__ hT, const float* __restrict__ Wout,
    const float* __restrict__ bout, const float* __restrict__ trans,
    const float* __restrict__ st, const float* __restrict__ et,
    float* __restrict__ out) {
  const int b = blockIdx.x;
  const int tid = threadIdx.x;
  const int wv = tid >> 6;       // wave 0 = forward/A-side, wave 1 = backward/B
  const int lane = tid & 63;
  const int l15 = lane & 15;
  const int kq = lane >> 4;

  __shared__ __align__(16) ushort_t wfrag[3][8][64][8];  // 24,576 B
  __shared__ float tA[2][64][50];                        // 25,600 B
  __shared__ float tB[2][64][50];                        // 25,600 B
  __shared__ float shx[64];
  __shared__ float shmisc[2];    // [0]=S_alpha, [1]=numerator-A partial

  const ushort_t* hb_base = hT + (size_t)b * 512 * 256;
  const int j = lane;
  const bool v = j < 48;
  const int jj = v ? j : 47;

  // ---- Wout B-fragments + bias (split across both waves) ----
  float bo3[3];
#pragma unroll
  for (int jt = 0; jt < 3; ++jt) bo3[jt] = bout[jt * 16 + l15];
#pragma unroll 1
  for (int f = wv; f < 24; f += 2) {
    const int jt = f >> 3, c = f & 7;
    const float* src = Wout + (jt * 16 + l15) * 256 + c * 32 + kq * 8;
    bf16x8 fr = pack8(*(const float4*)src, *(const float4*)(src + 4));
    *(uint4*)&wfrag[jt][c][lane][0] = __builtin_bit_cast(uint4, fr);
  }

  // ---- per-wave gather coefficient calibration (semantics-proof) ----
  float pcr[64];
  {
    float pm[4];
    const float pj = (float)j;
    pm[0] = pj;
    pm[1] = __shfl_xor(pj, 16, 64);
    pm[2] = __shfl_xor(pj, 32, 64);
    pm[3] = __shfl_xor(pj, 48, 64);
    if (wv == 0) {
      // forward: coef for slot = P[idx][j]
#define K4_CALF(m, k) { const int idx_ = (int)rotk<k>(pm[m]); \
      pcr[(m) * 16 + (k)] = (v && idx_ < 48) ? fexp2(trans[idx_ * 48 + j] * L2E) : 0.f; }
      K4_ALL(K4_CALF)
#undef K4_CALF
    } else {
      // backward: coef for slot = P[j][idx]
#define K4_CALB(m, k) { const int idx_ = (int)rotk<k>(pm[m]); \
      pcr[(m) * 16 + (k)] = (v && idx_ < 48) ? fexp2(trans[j * 48 + idx_] * L2E) : 0.f; }
      K4_ALL(K4_CALB)
#undef K4_CALB
    }
  }

  // ---- wave1: masks for t>=256 (t<256 always active: lengths >= 256) ----
  unsigned long long mq4 = 0, mq5 = 0, mq6 = 0, mq7 = 0;
  if (wv == 1) {
    mq4 = __ballot(words[b * 512 + 4 * 64 + lane] != 0);
    mq5 = __ballot(words[b * 512 + 5 * 64 + lane] != 0);
    mq6 = __ballot(words[b * 512 + 6 * 64 + lane] != 0);
    mq7 = __ballot(words[b * 512 + 7 * 64 + lane] != 0);
  }
  __syncthreads();   // wfrag ready

  // ---- produce one 64-t emis tile into dst (one full tile per wave) ----
  auto produce = [&](int tile, float (*dst)[50]) {
#pragma unroll
    for (int ts = 0; ts < 4; ++ts) {
      const int tt0 = tile * 64 + ts * 16;
      bf16x8 afr[8];
#pragma unroll
      for (int c = 0; c < 8; ++c)
        afr[c] = __builtin_bit_cast(bf16x8,
            *(const uint4*)(hb_base + (size_t)(tt0 + l15) * 256 + c * 32 + kq * 8));
#pragma unroll
      for (int jt = 0; jt < 3; ++jt) {
        f32x4 a2 = {bo3[jt], bo3[jt], bo3[jt], bo3[jt]};
#pragma unroll
        for (int c = 0; c < 8; ++c) {
          bf16x8 bfr = __builtin_bit_cast(bf16x8, *(const uint4*)&wfrag[jt][c][lane][0]);
          a2 = __builtin_amdgcn_mfma_f32_16x16x32_bf16(afr[c], bfr, a2, 0, 0, 0);
        }
#pragma unroll
        for (int r = 0; r < 4; ++r)
          dst[ts * 16 + kq * 4 + r][jt * 16 + l15] = a2[r];
      }
    }
  };

  if (wv == 0) produce(0, tA[0]); else produce(7, tB[0]);
  __syncthreads();   // first tiles ready

  // ---- chain inits ----
  float d, Ecur;
  int S = 0, e_pend = 0;
  float snum = 0.f;
  if (wv == 0) {
    d = v ? fexp2((st[j] + tA[0][0][jj]) * L2E) : 0.f;   // alpha_0
    Ecur = fexp2(tA[0][1][jj] * L2E);                    // E_1
  } else {
    d = v ? fexp2(et[j] * L2E) : 0.f;                    // w = exp(et)
    Ecur = fexp2(tB[0][63][jj] * L2E);                   // E_511
  }

#pragma unroll 1
  for (int p = 0; p < 4; ++p) {
    // ================= produce segment (+ numerator) =================
    if (wv == 0) {
      if (p < 3) produce(p + 1, tA[(p + 1) & 1]);
      {  // numerator A-side: tile p resident in tA[p&1]; all t<256 active
        const int t = p * 64 + lane;
        const int tg = tags[b * 512 + t];
        if (t == 0) {
          snum += st[tg] + tA[0][0][tg];
        } else {
          const int tp = tags[b * 512 + t - 1];
          snum += trans[tp * 48 + tg] + tA[p & 1][lane][tg];
        }
      }
    } else {
      if (p < 3) produce(6 - p, tB[((6 - p) & 1) ^ 1]);
      {  // numerator B-side: tile 7-p resident in tB[((7-p)&1)^1]
        const int tl = 7 - p;
        const int t = tl * 64 + lane;
        const unsigned long long mqq =
            (p == 0) ? mq7 : (p == 1) ? mq6 : (p == 2) ? mq5 : mq4;
        if ((mqq >> lane) & 1ull) {
          const int tg = tags[b * 512 + t];
          const int tp = tags[b * 512 + t - 1];
          snum += trans[tp * 48 + tg] + tB[(tl & 1) ^ 1][lane][tg];
        }
      }
    }
    __syncthreads();
    // ================= serial segment (both chains concurrent) =======
    if (wv == 0) {
      if (p == 0) {  // peel t = 1..7 (fold at t=2 is a no-op, e_pend=0)
        A_BODY(false, 2, false)
        A_BODY(true,  3, false)
        A_BODY(false, 4, false)
        A_BODY(false, 5, false)
        A_BODY(false, 6, false)
        A_BODY(false, 7, false)
        A_BODY(false, 8, false)
      }
#pragma unroll 1
      for (int gi = (p == 0) ? 1 : 0; gi < 8; ++gi) {
        const int G = p * 64 + gi * 8;
        A_BODY(false, G + 1, true)             // t=G (measure)
        A_BODY(false, G + 2, false)
        A_BODY(true,  G + 3, false)            // t=G+2 (fold)
        A_BODY(false, G + 4, false)
        A_BODY(false, G + 5, false)
        A_BODY(false, G + 6, false)
        A_BODY(false, G + 7, false)
        A_BODY(false, min(G + 8, 255), false)  // t=G+7
      }
    } else {
      const unsigned long long mq =
          (p == 0) ? mq7 : (p == 1) ? mq6 : (p == 2) ? mq5 : mq4;
#pragma unroll 1
      for (int gi = 0; gi < 8; ++gi) {
        const int t0 = 511 - p * 64 - gi * 8;
        const uint_t mm = (uint_t)(mq >> (56 - 8 * gi));
        B_BODY(false, t0 - 1, (mm >> 7) & 1u, true)    // t=t0 (measure)
        B_BODY(false, t0 - 2, (mm >> 6) & 1u, false)
        B_BODY(true,  t0 - 3, (mm >> 5) & 1u, false)   // fold
        B_BODY(false, t0 - 4, (mm >> 4) & 1u, false)
        B_BODY(false, t0 - 5, (mm >> 3) & 1u, false)
        B_BODY(false, t0 - 6, (mm >> 2) & 1u, false)
        B_BODY(false, t0 - 7, (mm >> 1) & 1u, false)
        B_BODY(false, max(t0 - 8, 256), (mm >> 0) & 1u, false)  // t=t0-7
      }
    }
    __syncthreads();
  }

  // ---- epilogue: combine x.y, exponents, numerator ----
  if (wv == 0) {
    float sr = snum;
#pragma unroll
    for (int dd = 32; dd; dd >>= 1) sr += __shfl_xor(sr, dd, 64);
    shx[j] = d;
    if (lane == 0) { shmisc[0] = (float)S; shmisc[1] = sr; }
  }
  __syncthreads();
  if (wv == 1) {
    float uf = d * shx[j];   // x_j * y_j (0 for invalid lanes)
    float sr = snum;
#pragma unroll
    for (int dd = 32; dd; dd >>= 1) {
      uf += __shfl_xor(uf, dd, 64);
      sr += __shfl_xor(sr, dd, 64);
    }
    if (lane == 0) {
      const int cnt = 256 + (int)(__popcll(mq4) + __popcll(mq5) +
                                  __popcll(mq6) + __popcll(mq7));
      const int lt = tags[b * 512 + cnt - 1];
      const float num = shmisc[1] + sr + et[lt];
      const float denom = (shmisc[0] + (float)S + flog2(uf)) * LN2;
      atomicAdd(out, (denom - num) * (1.0f / 256.0f));
    }
  }
}

// ---------------------------------------------------------------------------
extern "C" void kernel_launch(void* const* d_in, const int* in_sizes, int n_in,
                              void* d_out, int out_size, void* d_ws, size_t ws_size,
                              hipStream_t stream) {
  (void)in_sizes; (void)n_in; (void)out_size; (void)ws_size;
  const int*   words = (const int*)d_in[0];
  const int*   tags  = (const int*)d_in[1];
  // d_in[2] = mask (bool) -- unused; reconstructed as words != 0
  const float* emb   = (const float*)d_in[3];
  const float* Wih_f = (const float*)d_in[4];
  const float* Whh_f = (const float*)d_in[5];
  const float* bih_f = (const float*)d_in[6];
  const float* bhh_f = (const float*)d_in[7];
  const float* Wih_b = (const float*)d_in[8];
  const float* Whh_b = (const float*)d_in[9];
  const float* bih_b = (const float*)d_in[10];
  const float* bhh_b = (const float*)d_in[11];
  const float* Wout  = (const float*)d_in[12];
  const float* bout  = (const float*)d_in[13];
  const float* trans = (const float*)d_in[14];
  const float* st    = (const float*)d_in[15];
  const float* et    = (const float*)d_in[16];

  char* ws = (char*)d_ws;
  ushort_t* h_T = (ushort_t*)(ws);   // [256 b][512 t][256 k] bf16 = 64 MB

  k2_lstm  <<<256, 512, 0, stream>>>(words, emb,
                                     Wih_f, Whh_f, bih_f, bhh_f,
                                     Wih_b, Whh_b, bih_b, bhh_b,
                                     h_T, (float*)d_out);
  k4_fused <<<256, 128, 0, stream>>>(words, tags, h_T, Wout, bout,
                                     trans, st, et, (float*)d_out);
}